// Round 1
// baseline (570.718 us; speedup 1.0000x reference)
//
#include <hip/hip_runtime.h>

typedef unsigned short u16;
typedef unsigned int u32;
typedef __attribute__((ext_vector_type(8))) __bf16 bf16x8;
typedef __attribute__((ext_vector_type(4))) float f32x4;
typedef __attribute__((ext_vector_type(8))) unsigned short ushort8;
typedef __attribute__((ext_vector_type(4))) unsigned short ushort4v;
typedef __attribute__((ext_vector_type(4))) float float4v;

#define B_ 4
#define T_ 2048
#define C_ 1024
#define H_ 16
#define D_ 64
#define M_ (B_ * T_)

union ABUn { ushort8 u; bf16x8 b; };

__device__ __forceinline__ u16 f2bf(float f) {
  u32 u = __builtin_bit_cast(u32, f);
  u32 r = u + 0x7fffu + ((u >> 16) & 1u);
  return (u16)(r >> 16);
}

// ---------------- prep: cast x to bf16 ----------------
__global__ void cast_kernel(const float* __restrict__ in, u16* __restrict__ out, int n4) {
  int i = blockIdx.x * blockDim.x + threadIdx.x;
  if (i >= n4) return;
  float4v v = ((const float4v*)in)[i];
  ushort4v o;
  o[0] = f2bf(v[0]); o[1] = f2bf(v[1]); o[2] = f2bf(v[2]); o[3] = f2bf(v[3]);
  ((ushort4v*)out)[i] = o;
}

// ---------------- prep: transpose + cast weights ----------------
// src [Kd][Nd] f32 -> dst [Nd][Kd] bf16
__global__ void transpose_cast_kernel(const float* __restrict__ src, u16* __restrict__ dst,
                                      int Kd, int Nd) {
  __shared__ float tile[32][33];
  int n0 = blockIdx.x * 32, k0 = blockIdx.y * 32;
  int tx = threadIdx.x, ty = threadIdx.y;  // blockDim (32,8)
#pragma unroll
  for (int i = 0; i < 32; i += 8)
    tile[ty + i][tx] = src[(k0 + ty + i) * Nd + n0 + tx];
  __syncthreads();
#pragma unroll
  for (int i = 0; i < 32; i += 8)
    dst[(n0 + ty + i) * Kd + k0 + tx] = f2bf(tile[tx][ty + i]);
}

// ---------------- GEMM: A [M][1024] bf16, Bt [N][1024] bf16 ----------------
// EPI 0: scatter into Q (scaled 0.125) / K / V buffers [B*H][T][D] bf16
// EPI 1: Out[m][n] = acc + bias[n]  (f32)
template <int EPI>
__global__ __launch_bounds__(256, 2) void gemm_bt(
    const u16* __restrict__ A, const u16* __restrict__ Bt,
    u16* __restrict__ Qb, u16* __restrict__ Kb, u16* __restrict__ Vb,
    float* __restrict__ Out, const float* __restrict__ bias) {
  __shared__ u16 As[128 * 64];
  __shared__ u16 Bs[128 * 64];
  const int tid = threadIdx.x;
  const int lane = tid & 63, wave = tid >> 6;
  const int wm = wave >> 1, wn = wave & 1;
  const int lg = lane >> 4, lr = lane & 15;
  const int m0 = blockIdx.y * 128, n0 = blockIdx.x * 128;

  f32x4 acc[4][4];
  const f32x4 zero = {0.0f, 0.0f, 0.0f, 0.0f};
#pragma unroll
  for (int mi = 0; mi < 4; ++mi)
#pragma unroll
    for (int ni = 0; ni < 4; ++ni) acc[mi][ni] = zero;

  // staging: thread covers row srow, 32 cols starting at scol
  const int srow = tid >> 1;
  const int scol = (tid & 1) * 32;
  const u16* Ap = A + (m0 + srow) * 1024 + scol;
  const u16* Bp = Bt + (n0 + srow) * 1024 + scol;
  char* AsB = (char*)As;
  char* BsB = (char*)Bs;
  const u32 swz = (u32)((srow & 7) << 4);
  const u32 sbase = (u32)(srow * 128 + scol * 2);

  for (int k0 = 0; k0 < 1024; k0 += 64) {
    ushort8 a0 = *(const ushort8*)(Ap + k0);
    ushort8 a1 = *(const ushort8*)(Ap + k0 + 8);
    ushort8 a2 = *(const ushort8*)(Ap + k0 + 16);
    ushort8 a3 = *(const ushort8*)(Ap + k0 + 24);
    ushort8 b0 = *(const ushort8*)(Bp + k0);
    ushort8 b1 = *(const ushort8*)(Bp + k0 + 8);
    ushort8 b2 = *(const ushort8*)(Bp + k0 + 16);
    ushort8 b3 = *(const ushort8*)(Bp + k0 + 24);
    *(ushort8*)(AsB + ((sbase + 0) ^ swz)) = a0;
    *(ushort8*)(AsB + ((sbase + 16) ^ swz)) = a1;
    *(ushort8*)(AsB + ((sbase + 32) ^ swz)) = a2;
    *(ushort8*)(AsB + ((sbase + 48) ^ swz)) = a3;
    *(ushort8*)(BsB + ((sbase + 0) ^ swz)) = b0;
    *(ushort8*)(BsB + ((sbase + 16) ^ swz)) = b1;
    *(ushort8*)(BsB + ((sbase + 32) ^ swz)) = b2;
    *(ushort8*)(BsB + ((sbase + 48) ^ swz)) = b3;
    __syncthreads();
#pragma unroll
    for (int kk = 0; kk < 2; ++kk) {
      bf16x8 am[4], bn[4];
#pragma unroll
      for (int mi = 0; mi < 4; ++mi) {
        int row = wm * 64 + mi * 16 + lr;
        ABUn u;
        u.u = *(const ushort8*)(AsB + ((u32)(row * 128 + kk * 64 + lg * 16) ^ (u32)((row & 7) << 4)));
        am[mi] = u.b;
      }
#pragma unroll
      for (int ni = 0; ni < 4; ++ni) {
        int row = wn * 64 + ni * 16 + lr;
        ABUn u;
        u.u = *(const ushort8*)(BsB + ((u32)(row * 128 + kk * 64 + lg * 16) ^ (u32)((row & 7) << 4)));
        bn[ni] = u.b;
      }
#pragma unroll
      for (int mi = 0; mi < 4; ++mi)
#pragma unroll
        for (int ni = 0; ni < 4; ++ni)
          acc[mi][ni] = __builtin_amdgcn_mfma_f32_16x16x32_bf16(am[mi], bn[ni], acc[mi][ni], 0, 0, 0);
    }
    __syncthreads();
  }

  // epilogue: value acc[mi][ni][r] at m = frag row lg*4+r, n = frag col lr
#pragma unroll
  for (int mi = 0; mi < 4; ++mi)
#pragma unroll
    for (int ni = 0; ni < 4; ++ni)
#pragma unroll
      for (int r = 0; r < 4; ++r) {
        int m = m0 + wm * 64 + mi * 16 + lg * 4 + r;
        int n = n0 + wn * 64 + ni * 16 + lr;
        float v = acc[mi][ni][r];
        if (EPI == 0) {
          int part = n >> 10, c = n & 1023;
          int h = c >> 6, d = c & 63;
          int b = m >> 11, t = m & 2047;
          u16* dst = (part == 0) ? Qb : (part == 1) ? Kb : Vb;
          float s = (part == 0) ? 0.125f : 1.0f;  // fold 1/sqrt(D) into Q
          dst[((b * H_ + h) * T_ + t) * D_ + d] = f2bf(v * s);
        } else {
          Out[m * 1024 + n] = v + bias[n];
        }
      }
}

// ---------------- flash attention ----------------
// grid (T/64, B*H), block 256 (4 waves x 16 q-rows). KV chunk = 32.
__global__ __launch_bounds__(256) void attn_kernel(
    const u16* __restrict__ Qb, const u16* __restrict__ Kb,
    const u16* __restrict__ Vb, u16* __restrict__ Ob) {
  __shared__ u16 Ks[32 * 64];    // [kv][d], swizzled rows (128B)
  __shared__ u16 Vts[64 * 32];   // [d][kv], swizzled rows (64B)
  __shared__ u16 Ps[4][16 * 32]; // per-wave P [q][kv], swizzled rows (64B)
  const int bh = blockIdx.y;
  const int q0 = blockIdx.x * 64;
  const u16* Qh = Qb + bh * (T_ * D_);
  const u16* Kh = Kb + bh * (T_ * D_);
  const u16* Vh = Vb + bh * (T_ * D_);
  const int tid = threadIdx.x;
  const int lane = tid & 63, wave = tid >> 6;
  const int lg = lane >> 4, lr = lane & 15;

  // Q fragments (held in registers all kernel): rows q0 + wave*16 + lr
  bf16x8 qf[2];
  {
    int qrow = q0 + wave * 16 + lr;
    ABUn u0, u1;
    u0.u = *(const ushort8*)(Qh + qrow * 64 + lg * 8);
    u1.u = *(const ushort8*)(Qh + qrow * 64 + 32 + lg * 8);
    qf[0] = u0.b;
    qf[1] = u1.b;
  }

  f32x4 o[4];
  const f32x4 zero = {0.0f, 0.0f, 0.0f, 0.0f};
#pragma unroll
  for (int dt = 0; dt < 4; ++dt) o[dt] = zero;
  float mrow[4], lrow[4];
#pragma unroll
  for (int r = 0; r < 4; ++r) { mrow[r] = -1e30f; lrow[r] = 0.0f; }

  const int nchunk = q0 / 32 + 2;  // cover kv <= q0+63
  const int str = tid >> 3;        // staging kv row 0..31
  const int stc = (tid & 7) * 8;   // staging d col base
  char* KsB = (char*)Ks;
  char* VtsB = (char*)Vts;
  char* PsB = (char*)(Ps[wave]);

  for (int ch = 0; ch < nchunk; ++ch) {
    const int kv0 = ch * 32;
    {
      ushort8 kvv = *(const ushort8*)(Kh + (kv0 + str) * 64 + stc);
      *(ushort8*)(KsB + ((u32)(str * 128 + stc * 2) ^ (u32)((str & 7) << 4))) = kvv;
      ushort8 vvv = *(const ushort8*)(Vh + (kv0 + str) * 64 + stc);
#pragma unroll
      for (int j = 0; j < 8; ++j) {
        int d = stc + j;
        *(u16*)(VtsB + ((u32)(d * 64 + str * 2) ^ (u32)((d & 7) << 4))) = (u16)vvv[j];
      }
    }
    __syncthreads();

    // S = Q K^T : rows q (lg*4+r), cols kv (lr | 16+lr)
    f32x4 s0 = zero, s1 = zero;
#pragma unroll
    for (int kk = 0; kk < 2; ++kk) {
      int r0 = lr, r1 = 16 + lr;
      ABUn bu0, bu1;
      bu0.u = *(const ushort8*)(KsB + ((u32)(r0 * 128 + kk * 64 + lg * 16) ^ (u32)((r0 & 7) << 4)));
      bu1.u = *(const ushort8*)(KsB + ((u32)(r1 * 128 + kk * 64 + lg * 16) ^ (u32)((r1 & 7) << 4)));
      s0 = __builtin_amdgcn_mfma_f32_16x16x32_bf16(qf[kk], bu0.b, s0, 0, 0, 0);
      s1 = __builtin_amdgcn_mfma_f32_16x16x32_bf16(qf[kk], bu1.b, s1, 0, 0, 0);
    }

    // online softmax (per q-row; row lives on 16 lanes of a group)
    const int qgb = q0 + wave * 16 + lg * 4;
    float fac[4];
#pragma unroll
    for (int r = 0; r < 4; ++r) {
      int qg = qgb + r;
      float a0 = (kv0 + lr <= qg) ? s0[r] : -1e30f;
      float a1 = (kv0 + 16 + lr <= qg) ? s1[r] : -1e30f;
      float cm = fmaxf(a0, a1);
#pragma unroll
      for (int off = 1; off < 16; off <<= 1) cm = fmaxf(cm, __shfl_xor(cm, off));
      float mnew = fmaxf(mrow[r], cm);
      float f = __expf(mrow[r] - mnew);
      float p0 = __expf(a0 - mnew);
      float p1 = __expf(a1 - mnew);
      float ps = p0 + p1;
#pragma unroll
      for (int off = 1; off < 16; off <<= 1) ps += __shfl_xor(ps, off);
      lrow[r] = lrow[r] * f + ps;
      mrow[r] = mnew;
      fac[r] = f;
      int qr = lg * 4 + r;
      u32 rswz = (u32)((qr & 7) << 4);
      *(u16*)(PsB + ((u32)(qr * 64 + lr * 2) ^ rswz)) = f2bf(p0);
      *(u16*)(PsB + ((u32)(qr * 64 + (16 + lr) * 2) ^ rswz)) = f2bf(p1);
    }
#pragma unroll
    for (int dt = 0; dt < 4; ++dt)
#pragma unroll
      for (int r = 0; r < 4; ++r) o[dt][r] *= fac[r];

    // P went through LDS (transpose to A-frag layout); wave-internal hazard
    asm volatile("s_waitcnt lgkmcnt(0)" ::: "memory");
    ABUn pu;
    pu.u = *(const ushort8*)(PsB + ((u32)(lr * 64 + lg * 16) ^ (u32)((lr & 7) << 4)));
#pragma unroll
    for (int dt = 0; dt < 4; ++dt) {
      int vr = dt * 16 + lr;
      ABUn vu;
      vu.u = *(const ushort8*)(VtsB + ((u32)(vr * 64 + lg * 16) ^ (u32)((vr & 7) << 4)));
      o[dt] = __builtin_amdgcn_mfma_f32_16x16x32_bf16(pu.b, vu.b, o[dt], 0, 0, 0);
    }
    __syncthreads();
  }

  // epilogue: normalize and write heads-merged [B*T][C] bf16
  const int hh = bh & (H_ - 1);
  const int bb = bh >> 4;
#pragma unroll
  for (int r = 0; r < 4; ++r) {
    float inv = 1.0f / lrow[r];
    int trow = q0 + wave * 16 + lg * 4 + r;
    u16* orow = Ob + (bb * T_ + trow) * C_ + hh * 64;
#pragma unroll
    for (int dt = 0; dt < 4; ++dt) orow[dt * 16 + lr] = f2bf(o[dt][r] * inv);
  }
}

// ---------------- launch ----------------
extern "C" void kernel_launch(void* const* d_in, const int* in_sizes, int n_in,
                              void* d_out, int out_size, void* d_ws, size_t ws_size,
                              hipStream_t stream) {
  const float* x = (const float*)d_in[0];
  const float* w_qkv = (const float*)d_in[1];
  const float* w_proj = (const float*)d_in[2];
  const float* b_proj = (const float*)d_in[3];
  float* out = (float*)d_out;

  char* ws = (char*)d_ws;
  u16* xb = (u16*)(ws);                               // 16 MB  [M][C] bf16
  u16* wqT = (u16*)(ws + 16777216);                   // 6 MB   [3C][C] bf16
  u16* wpT = (u16*)(ws + 16777216 + 6291456);         // 2 MB   [C][C] bf16
  u16* Qb = (u16*)(ws + 25165824);                    // 16 MB  [B*H][T][D]
  u16* Kb = (u16*)(ws + 25165824 + 16777216);         // 16 MB
  u16* Vb = (u16*)(ws + 25165824 + 2 * 16777216);     // 16 MB
  u16* Ob = xb;  // reuse x's bf16 buffer (x fully consumed by QKV GEMM)

  cast_kernel<<<(M_ * C_ / 4 + 255) / 256, 256, 0, stream>>>(x, xb, M_ * C_ / 4);
  dim3 tb(32, 8);
  transpose_cast_kernel<<<dim3(3 * C_ / 32, C_ / 32), tb, 0, stream>>>(w_qkv, wqT, C_, 3 * C_);
  transpose_cast_kernel<<<dim3(C_ / 32, C_ / 32), tb, 0, stream>>>(w_proj, wpT, C_, C_);

  gemm_bt<0><<<dim3(3 * C_ / 128, M_ / 128), 256, 0, stream>>>(
      xb, wqT, Qb, Kb, Vb, nullptr, nullptr);

  attn_kernel<<<dim3(T_ / 64, B_ * H_), 256, 0, stream>>>(Qb, Kb, Vb, Ob);

  gemm_bt<1><<<dim3(C_ / 128, M_ / 128), 256, 0, stream>>>(
      Ob, wpT, nullptr, nullptr, nullptr, out, b_proj);
}

// Round 2
// 309.821 us; speedup vs baseline: 1.8421x; 1.8421x over previous
//
#include <hip/hip_runtime.h>

typedef unsigned short u16;
typedef unsigned int u32;
typedef __attribute__((ext_vector_type(8))) __bf16 bf16x8;
typedef __attribute__((ext_vector_type(4))) float f32x4;
typedef __attribute__((ext_vector_type(16))) float f32x16;
typedef __attribute__((ext_vector_type(8))) unsigned short ushort8;
typedef __attribute__((ext_vector_type(4))) unsigned short ushort4v;
typedef __attribute__((ext_vector_type(4))) unsigned int u32x4;
typedef __attribute__((ext_vector_type(4))) float float4v;

#define B_ 4
#define T_ 2048
#define C_ 1024
#define H_ 16
#define D_ 64
#define M_ (B_ * T_)

union ABUn { ushort8 u; bf16x8 b; };

__device__ __forceinline__ u16 f2bf(float f) {
  u32 u = __builtin_bit_cast(u32, f);
  u32 r = u + 0x7fffu + ((u >> 16) & 1u);
  return (u16)(r >> 16);
}

__device__ __forceinline__ float fexp2(float x) {
  float r; asm("v_exp_f32 %0, %1" : "=v"(r) : "v"(x)); return r;
}

__device__ __forceinline__ u32 pkbf(float lo, float hi_) {
  u32 r; asm("v_cvt_pk_bf16_f32 %0, %1, %2" : "=v"(r) : "v"(lo), "v"(hi_)); return r;
}

__device__ __forceinline__ void gl16(const u16* g, u16* l) {
  __builtin_amdgcn_global_load_lds((const __attribute__((address_space(1))) void*)g,
                                   (__attribute__((address_space(3))) void*)l, 16, 0, 0);
}

// ---------------- prep: cast x to bf16 ----------------
__global__ void cast_kernel(const float* __restrict__ in, u16* __restrict__ out, int n4) {
  int i = blockIdx.x * blockDim.x + threadIdx.x;
  if (i >= n4) return;
  float4v v = ((const float4v*)in)[i];
  ushort4v o;
  o[0] = f2bf(v[0]); o[1] = f2bf(v[1]); o[2] = f2bf(v[2]); o[3] = f2bf(v[3]);
  ((ushort4v*)out)[i] = o;
}

// ---------------- prep: transpose + cast weights ----------------
__global__ void transpose_cast_kernel(const float* __restrict__ src, u16* __restrict__ dst,
                                      int Kd, int Nd) {
  __shared__ float tile[32][33];
  int n0 = blockIdx.x * 32, k0 = blockIdx.y * 32;
  int tx = threadIdx.x, ty = threadIdx.y;  // blockDim (32,8)
#pragma unroll
  for (int i = 0; i < 32; i += 8)
    tile[ty + i][tx] = src[(k0 + ty + i) * Nd + n0 + tx];
  __syncthreads();
#pragma unroll
  for (int i = 0; i < 32; i += 8)
    dst[(n0 + ty + i) * Kd + k0 + tx] = f2bf(tile[tx][ty + i]);
}

// ---------------- GEMM: A [M][1024] bf16, Bt [N][1024] bf16 ----------------
// EPI 0: scatter into Q (scaled 0.125*log2e) / K [bh][t][d]; V transposed [bh][d][T]
// EPI 1: Out[m][n] = acc + bias[n]  (f32)
template <int EPI>
__global__ __launch_bounds__(256, 2) void gemm_bt(
    const u16* __restrict__ A, const u16* __restrict__ Bt,
    u16* __restrict__ Qb, u16* __restrict__ Kb, u16* __restrict__ Vb,
    float* __restrict__ Out, const float* __restrict__ bias) {
  __shared__ u16 As[128 * 64];
  __shared__ u16 Bs[128 * 64];
  const int tid = threadIdx.x;
  const int lane = tid & 63, wave = tid >> 6;
  const int wm = wave >> 1, wn = wave & 1;
  const int lg = lane >> 4, lr = lane & 15;
  const int m0 = blockIdx.y * 128, n0 = blockIdx.x * 128;

  f32x4 acc[4][4];
  const f32x4 zero = {0.0f, 0.0f, 0.0f, 0.0f};
#pragma unroll
  for (int mi = 0; mi < 4; ++mi)
#pragma unroll
    for (int ni = 0; ni < 4; ++ni) acc[mi][ni] = zero;

  const int srow = tid >> 1;
  const int scol = (tid & 1) * 32;
  const u16* Ap = A + (m0 + srow) * 1024 + scol;
  const u16* Bp = Bt + (n0 + srow) * 1024 + scol;
  char* AsB = (char*)As;
  char* BsB = (char*)Bs;
  const u32 swz = (u32)((srow & 7) << 4);
  const u32 sbase = (u32)(srow * 128 + scol * 2);

  for (int k0 = 0; k0 < 1024; k0 += 64) {
    ushort8 a0 = *(const ushort8*)(Ap + k0);
    ushort8 a1 = *(const ushort8*)(Ap + k0 + 8);
    ushort8 a2 = *(const ushort8*)(Ap + k0 + 16);
    ushort8 a3 = *(const ushort8*)(Ap + k0 + 24);
    ushort8 b0 = *(const ushort8*)(Bp + k0);
    ushort8 b1 = *(const ushort8*)(Bp + k0 + 8);
    ushort8 b2 = *(const ushort8*)(Bp + k0 + 16);
    ushort8 b3 = *(const ushort8*)(Bp + k0 + 24);
    *(ushort8*)(AsB + ((sbase + 0) ^ swz)) = a0;
    *(ushort8*)(AsB + ((sbase + 16) ^ swz)) = a1;
    *(ushort8*)(AsB + ((sbase + 32) ^ swz)) = a2;
    *(ushort8*)(AsB + ((sbase + 48) ^ swz)) = a3;
    *(ushort8*)(BsB + ((sbase + 0) ^ swz)) = b0;
    *(ushort8*)(BsB + ((sbase + 16) ^ swz)) = b1;
    *(ushort8*)(BsB + ((sbase + 32) ^ swz)) = b2;
    *(ushort8*)(BsB + ((sbase + 48) ^ swz)) = b3;
    __syncthreads();
#pragma unroll
    for (int kk = 0; kk < 2; ++kk) {
      bf16x8 am[4], bn[4];
#pragma unroll
      for (int mi = 0; mi < 4; ++mi) {
        int row = wm * 64 + mi * 16 + lr;
        ABUn u;
        u.u = *(const ushort8*)(AsB + ((u32)(row * 128 + kk * 64 + lg * 16) ^ (u32)((row & 7) << 4)));
        am[mi] = u.b;
      }
#pragma unroll
      for (int ni = 0; ni < 4; ++ni) {
        int row = wn * 64 + ni * 16 + lr;
        ABUn u;
        u.u = *(const ushort8*)(BsB + ((u32)(row * 128 + kk * 64 + lg * 16) ^ (u32)((row & 7) << 4)));
        bn[ni] = u.b;
      }
#pragma unroll
      for (int mi = 0; mi < 4; ++mi)
#pragma unroll
        for (int ni = 0; ni < 4; ++ni)
          acc[mi][ni] = __builtin_amdgcn_mfma_f32_16x16x32_bf16(am[mi], bn[ni], acc[mi][ni], 0, 0, 0);
    }
    __syncthreads();
  }

#pragma unroll
  for (int mi = 0; mi < 4; ++mi)
#pragma unroll
    for (int ni = 0; ni < 4; ++ni)
#pragma unroll
      for (int r = 0; r < 4; ++r) {
        int m = m0 + wm * 64 + mi * 16 + lg * 4 + r;
        int n = n0 + wn * 64 + ni * 16 + lr;
        float v = acc[mi][ni][r];
        if (EPI == 0) {
          int part = n >> 10, c = n & 1023;
          int h = c >> 6, d = c & 63;
          int b = m >> 11, t = m & 2047;
          if (part == 0)
            Qb[((b * H_ + h) * T_ + t) * D_ + d] = f2bf(v * 0.18033688f);  // 0.125*log2(e)
          else if (part == 1)
            Kb[((b * H_ + h) * T_ + t) * D_ + d] = f2bf(v);
          else
            Vb[((b * H_ + h) * D_ + d) * T_ + t] = f2bf(v);  // V transposed
        } else {
          Out[m * 1024 + n] = v + bias[n];
        }
      }
}

// ---------------- flash attention v2 ----------------
// 4 waves x 64 q-rows = 256 q/block; KVBLK=64; swapped QK^T (S^T in regs);
// double-buffered LDS K + V^T tiles via global_load_lds w/ pre-swizzled source.
__global__ __launch_bounds__(256, 2) void attn_kernel(
    const u16* __restrict__ Qb, const u16* __restrict__ Kb,
    const u16* __restrict__ Vt, u16* __restrict__ Ob) {
  __shared__ u16 smem[4][4096];  // [0..1]=K dbuf, [2..3]=V^T dbuf; reused as epi scratch
  const int bh = blockIdx.y;
  const int q0 = (7 - (int)blockIdx.x) * 256;  // heavy blocks first
  const int tid = threadIdx.x;
  const int lane = tid & 63, wave = tid >> 6;
  const int hi = lane >> 5, ln = lane & 31;
  const int qw0 = q0 + wave * 64;
  const int hh = bh & (H_ - 1), bb = bh >> 4;

  const u16* Qh = Qb + bh * (T_ * D_);
  const u16* Kh = Kb + bh * (T_ * D_);
  const u16* Vh = Vt + bh * (T_ * D_);

  // Q B-fragments: lane = q-col ln; k = d = ks*16 + hi*8 + j
  bf16x8 qf[2][4];
#pragma unroll
  for (int qt = 0; qt < 2; ++qt) {
    const u16* qr = Qh + (qw0 + qt * 32 + ln) * 64 + hi * 8;
#pragma unroll
    for (int ks = 0; ks < 4; ++ks)
      qf[qt][ks] = __builtin_bit_cast(bf16x8, *(const ushort8*)(qr + ks * 16));
  }

  f32x16 o[2][2];
#pragma unroll
  for (int dt = 0; dt < 2; ++dt)
#pragma unroll
    for (int qt = 0; qt < 2; ++qt)
#pragma unroll
      for (int i = 0; i < 16; ++i) o[dt][qt][i] = 0.0f;
  float m[2] = {-1e30f, -1e30f}, l[2] = {0.0f, 0.0f};

  const int nchunk = q0 / 64 + 4;
  const int slot0 = wave * 128;  // this wave's staging slots (x2 instrs of 64)

  // prologue: stage chunk 0 into buf 0
#pragma unroll
  for (int j = 0; j < 2; ++j) {
    int slot = slot0 + j * 64 + lane;
    int r = slot >> 3, sp = slot & 7;
    int sl = sp ^ (r & 7);
    gl16(Kh + r * 64 + sl * 8, &smem[0][(slot0 + j * 64) * 8]);
    gl16(Vh + r * 2048 + sl * 8, &smem[2][(slot0 + j * 64) * 8]);
  }
  __syncthreads();

  for (int ch = 0; ch < nchunk; ++ch) {
    const int kv0 = ch * 64;
    const int cur = ch & 1;
    if (ch + 1 < nchunk) {  // async prefetch next chunk into other buffer
      const int kn = kv0 + 64;
#pragma unroll
      for (int j = 0; j < 2; ++j) {
        int slot = slot0 + j * 64 + lane;
        int r = slot >> 3, sp = slot & 7;
        int sl = sp ^ (r & 7);
        gl16(Kh + (kn + r) * 64 + sl * 8, &smem[cur ^ 1][(slot0 + j * 64) * 8]);
        gl16(Vh + r * 2048 + kn + sl * 8, &smem[2 + (cur ^ 1)][(slot0 + j * 64) * 8]);
      }
    }
    if (kv0 <= qw0 + 63) {  // wave-uniform: skip fully-masked chunks
      const char* Kc = (const char*)smem[cur];
      const char* Vc = (const char*)smem[2 + cur];
      bf16x8 kf[2][4];
#pragma unroll
      for (int sub = 0; sub < 2; ++sub) {
        int r = sub * 32 + ln;
        u32 rs = (u32)((r & 7) << 4);
#pragma unroll
        for (int ks = 0; ks < 4; ++ks)
          kf[sub][ks] = __builtin_bit_cast(bf16x8,
              *(const ushort8*)(Kc + r * 128 + (u32)((ks * 32 + hi * 16) ^ rs)));
      }
      const bool partial = (kv0 + 63) > qw0;
      bf16x8 pb[2][4];
#pragma unroll
      for (int qt = 0; qt < 2; ++qt) {
        f32x16 s0, s1;
#pragma unroll
        for (int i = 0; i < 16; ++i) { s0[i] = 0.0f; s1[i] = 0.0f; }
#pragma unroll
        for (int ks = 0; ks < 4; ++ks) {
          s0 = __builtin_amdgcn_mfma_f32_32x32x16_bf16(kf[0][ks], qf[qt][ks], s0, 0, 0, 0);
          s1 = __builtin_amdgcn_mfma_f32_32x32x16_bf16(kf[1][ks], qf[qt][ks], s1, 0, 0, 0);
        }
        const int qg = qw0 + qt * 32 + ln;
        if (partial) {
#pragma unroll
          for (int r = 0; r < 16; ++r) {
            int R = (r & 3) + 8 * (r >> 2) + 4 * hi;
            s0[r] = (kv0 + R > qg) ? -1e30f : s0[r];
            s1[r] = (kv0 + 32 + R > qg) ? -1e30f : s1[r];
          }
        }
        float cm = -1e30f;
#pragma unroll
        for (int r = 0; r < 16; ++r) cm = fmaxf(cm, fmaxf(s0[r], s1[r]));
        cm = fmaxf(cm, __shfl_xor(cm, 32));
        float mn = fmaxf(m[qt], cm);
        float fsc = fexp2(m[qt] - mn);
        m[qt] = mn;
        float ssum = 0.0f;
#pragma unroll
        for (int r = 0; r < 16; ++r) {
          s0[r] = fexp2(s0[r] - mn);
          s1[r] = fexp2(s1[r] - mn);
          ssum += s0[r] + s1[r];
        }
        ssum += __shfl_xor(ssum, 32);
        l[qt] = l[qt] * fsc + ssum;
#pragma unroll
        for (int dt = 0; dt < 2; ++dt)
#pragma unroll
          for (int i = 0; i < 16; ++i) o[dt][qt][i] *= fsc;
        // pack P->bf16 and lane-pair exchange -> B-fragments (k = kv = ks*16+hi*8+j)
#pragma unroll
        for (int sub = 0; sub < 2; ++sub) {
          u32 a0, a1, a2, a3, a4, a5, a6, a7;
          if (sub == 0) {
            a0 = pkbf(s0[0], s0[1]);  a1 = pkbf(s0[2], s0[3]);
            a2 = pkbf(s0[4], s0[5]);  a3 = pkbf(s0[6], s0[7]);
            a4 = pkbf(s0[8], s0[9]);  a5 = pkbf(s0[10], s0[11]);
            a6 = pkbf(s0[12], s0[13]); a7 = pkbf(s0[14], s0[15]);
          } else {
            a0 = pkbf(s1[0], s1[1]);  a1 = pkbf(s1[2], s1[3]);
            a2 = pkbf(s1[4], s1[5]);  a3 = pkbf(s1[6], s1[7]);
            a4 = pkbf(s1[8], s1[9]);  a5 = pkbf(s1[10], s1[11]);
            a6 = pkbf(s1[12], s1[13]); a7 = pkbf(s1[14], s1[15]);
          }
          u32 x0 = __shfl_xor(hi ? a0 : a2, 32);
          u32 x1 = __shfl_xor(hi ? a1 : a3, 32);
          u32 x2 = __shfl_xor(hi ? a4 : a6, 32);
          u32 x3 = __shfl_xor(hi ? a5 : a7, 32);
          u32x4 w0, w1;
          w0[0] = hi ? x0 : a0; w0[1] = hi ? x1 : a1;
          w0[2] = hi ? a2 : x0; w0[3] = hi ? a3 : x1;
          w1[0] = hi ? x2 : a4; w1[1] = hi ? x3 : a5;
          w1[2] = hi ? a6 : x2; w1[3] = hi ? a7 : x3;
          pb[qt][sub * 2 + 0] = __builtin_bit_cast(bf16x8, w0);
          pb[qt][sub * 2 + 1] = __builtin_bit_cast(bf16x8, w1);
        }
      }
      // PV: O^T[d][q] += V^T[d][kv] * P^T[kv][q]
#pragma unroll
      for (int dt = 0; dt < 2; ++dt) {
        int r = dt * 32 + ln;
        u32 rs = (u32)((r & 7) << 4);
#pragma unroll
        for (int ks = 0; ks < 4; ++ks) {
          bf16x8 vfk = __builtin_bit_cast(bf16x8,
              *(const ushort8*)(Vc + r * 128 + (u32)((ks * 32 + hi * 16) ^ rs)));
#pragma unroll
          for (int qt = 0; qt < 2; ++qt)
            o[dt][qt] = __builtin_amdgcn_mfma_f32_32x32x16_bf16(vfk, pb[qt][ks], o[dt][qt], 0, 0, 0);
        }
      }
    }
    __syncthreads();
  }

  // epilogue: normalize, transpose O^T -> O through per-wave LDS, coalesced store
  __syncthreads();
  char* Wb = (char*)smem[wave];  // 8KB per wave
#pragma unroll
  for (int qt = 0; qt < 2; ++qt) {
    float inv = 1.0f / l[qt];
    int q = qt * 32 + ln;
    u32 rs = (u32)((q & 7) << 4);
#pragma unroll
    for (int dt = 0; dt < 2; ++dt)
#pragma unroll
      for (int p = 0; p < 8; ++p) {
        u32 w = pkbf(o[dt][qt][2 * p] * inv, o[dt][qt][2 * p + 1] * inv);
        int d = dt * 32 + ((2 * p) & 3) + 8 * (p >> 1) + 4 * hi;
        *(u32*)(Wb + ((u32)(q * 128 + d * 2) ^ rs)) = w;
      }
  }
#pragma unroll
  for (int j = 0; j < 8; ++j) {
    int idx = j * 64 + lane;
    int row = idx >> 3, sp = idx & 7;
    ushort8 v = *(const ushort8*)(Wb + row * 128 + (u32)((sp * 16) ^ ((row & 7) << 4)));
    *(ushort8*)(Ob + (bb * T_ + qw0 + row) * C_ + hh * 64 + sp * 8) = v;
  }
}

// ---------------- launch ----------------
extern "C" void kernel_launch(void* const* d_in, const int* in_sizes, int n_in,
                              void* d_out, int out_size, void* d_ws, size_t ws_size,
                              hipStream_t stream) {
  const float* x = (const float*)d_in[0];
  const float* w_qkv = (const float*)d_in[1];
  const float* w_proj = (const float*)d_in[2];
  const float* b_proj = (const float*)d_in[3];
  float* out = (float*)d_out;

  char* ws = (char*)d_ws;
  u16* xb = (u16*)(ws);                               // 16 MB  [M][C] bf16
  u16* wqT = (u16*)(ws + 16777216);                   // 6 MB   [3C][C] bf16
  u16* wpT = (u16*)(ws + 16777216 + 6291456);         // 2 MB   [C][C] bf16
  u16* Qb = (u16*)(ws + 25165824);                    // 16 MB  [B*H][T][D]
  u16* Kb = (u16*)(ws + 25165824 + 16777216);         // 16 MB  [B*H][T][D]
  u16* Vt = (u16*)(ws + 25165824 + 2 * 16777216);     // 16 MB  [B*H][D][T] (transposed)
  u16* Ob = xb;  // reuse x's bf16 buffer

  cast_kernel<<<(M_ * C_ / 4 + 255) / 256, 256, 0, stream>>>(x, xb, M_ * C_ / 4);
  dim3 tb(32, 8);
  transpose_cast_kernel<<<dim3(3 * C_ / 32, C_ / 32), tb, 0, stream>>>(w_qkv, wqT, C_, 3 * C_);
  transpose_cast_kernel<<<dim3(C_ / 32, C_ / 32), tb, 0, stream>>>(w_proj, wpT, C_, C_);

  gemm_bt<0><<<dim3(3 * C_ / 128, M_ / 128), 256, 0, stream>>>(
      xb, wqT, Qb, Kb, Vt, nullptr, nullptr);

  attn_kernel<<<dim3(T_ / 256, B_ * H_), 256, 0, stream>>>(Qb, Kb, Vt, Ob);

  gemm_bt<1><<<dim3(C_ / 128, M_ / 128), 256, 0, stream>>>(
      Ob, wpT, nullptr, nullptr, nullptr, out, b_proj);
}

// Round 3
// 283.093 us; speedup vs baseline: 2.0160x; 1.0944x over previous
//
#include <hip/hip_runtime.h>

typedef unsigned short u16;
typedef unsigned int u32;
typedef __attribute__((ext_vector_type(8))) __bf16 bf16x8;
typedef __attribute__((ext_vector_type(4))) float f32x4;
typedef __attribute__((ext_vector_type(16))) float f32x16;
typedef __attribute__((ext_vector_type(8))) unsigned short ushort8;
typedef __attribute__((ext_vector_type(4))) unsigned short ushort4v;
typedef __attribute__((ext_vector_type(4))) unsigned int u32x4;
typedef __attribute__((ext_vector_type(4))) float float4v;

#define B_ 4
#define T_ 2048
#define C_ 1024
#define H_ 16
#define D_ 64
#define M_ (B_ * T_)

union ABUn { ushort8 u; bf16x8 b; };

__device__ __forceinline__ u16 f2bf(float f) {
  u32 u = __builtin_bit_cast(u32, f);
  u32 r = u + 0x7fffu + ((u >> 16) & 1u);
  return (u16)(r >> 16);
}

__device__ __forceinline__ float fexp2(float x) {
  float r; asm("v_exp_f32 %0, %1" : "=v"(r) : "v"(x)); return r;
}

__device__ __forceinline__ u32 pkbf(float lo, float hi_) {
  u32 r; asm("v_cvt_pk_bf16_f32 %0, %1, %2" : "=v"(r) : "v"(lo), "v"(hi_)); return r;
}

__device__ __forceinline__ void gl16(const u16* g, u16* l) {
  __builtin_amdgcn_global_load_lds((const __attribute__((address_space(1))) void*)g,
                                   (__attribute__((address_space(3))) void*)l, 16, 0, 0);
}

// ---------------- prep: cast x to bf16 ----------------
__global__ void cast_kernel(const float* __restrict__ in, u16* __restrict__ out, int n4) {
  int i = blockIdx.x * blockDim.x + threadIdx.x;
  if (i >= n4) return;
  float4v v = ((const float4v*)in)[i];
  ushort4v o;
  o[0] = f2bf(v[0]); o[1] = f2bf(v[1]); o[2] = f2bf(v[2]); o[3] = f2bf(v[3]);
  ((ushort4v*)out)[i] = o;
}

// ---------------- prep: transpose + cast weights ----------------
__global__ void transpose_cast_kernel(const float* __restrict__ src, u16* __restrict__ dst,
                                      int Kd, int Nd) {
  __shared__ float tile[32][33];
  int n0 = blockIdx.x * 32, k0 = blockIdx.y * 32;
  int tx = threadIdx.x, ty = threadIdx.y;  // blockDim (32,8)
#pragma unroll
  for (int i = 0; i < 32; i += 8)
    tile[ty + i][tx] = src[(k0 + ty + i) * Nd + n0 + tx];
  __syncthreads();
#pragma unroll
  for (int i = 0; i < 32; i += 8)
    dst[(n0 + ty + i) * Kd + k0 + tx] = f2bf(tile[tx][ty + i]);
}

// ---------------- GEMM: A [M][1024] bf16, Bt [N][1024] bf16 ----------------
// m97 structure: global_load_lds width-16 staging (linear LDS dest,
// pre-swizzled global source so swizzled ds_read_b128 is conflict-free).
// EPI 0: scatter into Q (scaled 0.125*log2e) / K [bh][t][d]; V transposed [bh][d][T]
// EPI 1: Out[m][n] = acc + bias[n]  (f32)
template <int EPI>
__global__ __launch_bounds__(256, 2) void gemm_bt(
    const u16* __restrict__ A, const u16* __restrict__ Bt,
    u16* __restrict__ Qb, u16* __restrict__ Kb, u16* __restrict__ Vb,
    float* __restrict__ Out, const float* __restrict__ bias) {
  __shared__ u16 As[128 * 64];
  __shared__ u16 Bs[128 * 64];
  const int tid = threadIdx.x;
  const int lane = tid & 63, wave = tid >> 6;
  const int wm = wave >> 1, wn = wave & 1;
  const int lg = lane >> 4, lr = lane & 15;
  const int m0 = blockIdx.y * 128, n0 = blockIdx.x * 128;

  f32x4 acc[4][4];
  const f32x4 zero = {0.0f, 0.0f, 0.0f, 0.0f};
#pragma unroll
  for (int mi = 0; mi < 4; ++mi)
#pragma unroll
    for (int ni = 0; ni < 4; ++ni) acc[mi][ni] = zero;

  // staging via global_load_lds: slot s = wave*256 + j*64 + lane covers
  // LDS row = s>>3, 16B-chunk sp = s&7; global source chunk = sp ^ (row&7).
  const u16* Abase = A + m0 * 1024;
  const u16* Bbase = Bt + n0 * 1024;
  int aoff[4];
#pragma unroll
  for (int j = 0; j < 4; ++j) {
    int s = wave * 256 + j * 64 + lane;
    int row = s >> 3, sp = s & 7;
    aoff[j] = row * 1024 + (sp ^ (row & 7)) * 8;
  }
  char* AsB = (char*)As;
  char* BsB = (char*)Bs;

  for (int k0 = 0; k0 < 1024; k0 += 64) {
#pragma unroll
    for (int j = 0; j < 4; ++j) {
      u16* ldst_a = &As[(wave * 256 + j * 64) * 8];
      u16* ldst_b = &Bs[(wave * 256 + j * 64) * 8];
      gl16(Abase + aoff[j] + k0, ldst_a);
      gl16(Bbase + aoff[j] + k0, ldst_b);
    }
    __syncthreads();  // drains vmcnt -> LDS tiles ready
#pragma unroll
    for (int kk = 0; kk < 2; ++kk) {
      bf16x8 am[4], bn[4];
#pragma unroll
      for (int mi = 0; mi < 4; ++mi) {
        int row = wm * 64 + mi * 16 + lr;
        ABUn u;
        u.u = *(const ushort8*)(AsB + ((u32)(row * 128 + ((kk * 64 + lg * 16) ^ ((row & 7) << 4)))));
        am[mi] = u.b;
      }
#pragma unroll
      for (int ni = 0; ni < 4; ++ni) {
        int row = wn * 64 + ni * 16 + lr;
        ABUn u;
        u.u = *(const ushort8*)(BsB + ((u32)(row * 128 + ((kk * 64 + lg * 16) ^ ((row & 7) << 4)))));
        bn[ni] = u.b;
      }
#pragma unroll
      for (int mi = 0; mi < 4; ++mi)
#pragma unroll
        for (int ni = 0; ni < 4; ++ni)
          acc[mi][ni] = __builtin_amdgcn_mfma_f32_16x16x32_bf16(am[mi], bn[ni], acc[mi][ni], 0, 0, 0);
    }
    __syncthreads();
  }

#pragma unroll
  for (int mi = 0; mi < 4; ++mi)
#pragma unroll
    for (int ni = 0; ni < 4; ++ni) {
      int m = m0 + wm * 64 + mi * 16 + lg * 4;  // base t (r adds 0..3)
      int n = n0 + wn * 64 + ni * 16 + lr;
      if (EPI == 0) {
        int part = n >> 10, c = n & 1023;
        int h = c >> 6, d = c & 63;
        int b = m >> 11, t = m & 2047;
        if (part == 2) {
          // V transposed: 4 consecutive t are contiguous -> packed 8B store
          ushort4v pv;
#pragma unroll
          for (int r = 0; r < 4; ++r) pv[r] = f2bf(acc[mi][ni][r]);
          *(ushort4v*)&Vb[((b * H_ + h) * D_ + d) * T_ + t] = pv;
        } else {
#pragma unroll
          for (int r = 0; r < 4; ++r) {
            float v = acc[mi][ni][r];
            if (part == 0)
              Qb[((b * H_ + h) * T_ + t + r) * D_ + d] = f2bf(v * 0.18033688f);  // 0.125*log2(e)
            else
              Kb[((b * H_ + h) * T_ + t + r) * D_ + d] = f2bf(v);
          }
        }
      } else {
#pragma unroll
        for (int r = 0; r < 4; ++r)
          Out[(m + r) * 1024 + n] = acc[mi][ni][r] + bias[n];
      }
    }
}

// ---------------- flash attention v2 ----------------
// 4 waves x 64 q-rows = 256 q/block; KVBLK=64; swapped QK^T (S^T in regs);
// double-buffered LDS K + V^T tiles via global_load_lds w/ pre-swizzled source.
__global__ __launch_bounds__(256, 2) void attn_kernel(
    const u16* __restrict__ Qb, const u16* __restrict__ Kb,
    const u16* __restrict__ Vt, u16* __restrict__ Ob) {
  __shared__ u16 smem[4][4096];  // [0..1]=K dbuf, [2..3]=V^T dbuf; reused as epi scratch
  const int bh = blockIdx.y;
  const int q0 = (7 - (int)blockIdx.x) * 256;  // heavy blocks first
  const int tid = threadIdx.x;
  const int lane = tid & 63, wave = tid >> 6;
  const int hi = lane >> 5, ln = lane & 31;
  const int qw0 = q0 + wave * 64;
  const int hh = bh & (H_ - 1), bb = bh >> 4;

  const u16* Qh = Qb + bh * (T_ * D_);
  const u16* Kh = Kb + bh * (T_ * D_);
  const u16* Vh = Vt + bh * (T_ * D_);

  // Q B-fragments: lane = q-col ln; k = d = ks*16 + hi*8 + j
  bf16x8 qf[2][4];
#pragma unroll
  for (int qt = 0; qt < 2; ++qt) {
    const u16* qr = Qh + (qw0 + qt * 32 + ln) * 64 + hi * 8;
#pragma unroll
    for (int ks = 0; ks < 4; ++ks)
      qf[qt][ks] = __builtin_bit_cast(bf16x8, *(const ushort8*)(qr + ks * 16));
  }

  f32x16 o[2][2];
#pragma unroll
  for (int dt = 0; dt < 2; ++dt)
#pragma unroll
    for (int qt = 0; qt < 2; ++qt)
#pragma unroll
      for (int i = 0; i < 16; ++i) o[dt][qt][i] = 0.0f;
  float m[2] = {-1e30f, -1e30f}, l[2] = {0.0f, 0.0f};

  const int nchunk = q0 / 64 + 4;
  const int slot0 = wave * 128;  // this wave's staging slots (x2 instrs of 64)

  // prologue: stage chunk 0 into buf 0
#pragma unroll
  for (int j = 0; j < 2; ++j) {
    int slot = slot0 + j * 64 + lane;
    int r = slot >> 3, sp = slot & 7;
    int sl = sp ^ (r & 7);
    gl16(Kh + r * 64 + sl * 8, &smem[0][(slot0 + j * 64) * 8]);
    gl16(Vh + r * 2048 + sl * 8, &smem[2][(slot0 + j * 64) * 8]);
  }
  __syncthreads();

  for (int ch = 0; ch < nchunk; ++ch) {
    const int kv0 = ch * 64;
    const int cur = ch & 1;
    if (ch + 1 < nchunk) {  // async prefetch next chunk into other buffer
      const int kn = kv0 + 64;
#pragma unroll
      for (int j = 0; j < 2; ++j) {
        int slot = slot0 + j * 64 + lane;
        int r = slot >> 3, sp = slot & 7;
        int sl = sp ^ (r & 7);
        gl16(Kh + (kn + r) * 64 + sl * 8, &smem[cur ^ 1][(slot0 + j * 64) * 8]);
        gl16(Vh + r * 2048 + kn + sl * 8, &smem[2 + (cur ^ 1)][(slot0 + j * 64) * 8]);
      }
    }
    if (kv0 <= qw0 + 63) {  // wave-uniform: skip fully-masked chunks
      const char* Kc = (const char*)smem[cur];
      const char* Vc = (const char*)smem[2 + cur];
      bf16x8 kf[2][4];
#pragma unroll
      for (int sub = 0; sub < 2; ++sub) {
        int r = sub * 32 + ln;
        u32 rs = (u32)((r & 7) << 4);
#pragma unroll
        for (int ks = 0; ks < 4; ++ks)
          kf[sub][ks] = __builtin_bit_cast(bf16x8,
              *(const ushort8*)(Kc + r * 128 + (u32)((ks * 32 + hi * 16) ^ rs)));
      }
      const bool partial = (kv0 + 63) > qw0;
      bf16x8 pb[2][4];
#pragma unroll
      for (int qt = 0; qt < 2; ++qt) {
        f32x16 s0, s1;
#pragma unroll
        for (int i = 0; i < 16; ++i) { s0[i] = 0.0f; s1[i] = 0.0f; }
#pragma unroll
        for (int ks = 0; ks < 4; ++ks) {
          s0 = __builtin_amdgcn_mfma_f32_32x32x16_bf16(kf[0][ks], qf[qt][ks], s0, 0, 0, 0);
          s1 = __builtin_amdgcn_mfma_f32_32x32x16_bf16(kf[1][ks], qf[qt][ks], s1, 0, 0, 0);
        }
        const int qg = qw0 + qt * 32 + ln;
        if (partial) {
#pragma unroll
          for (int r = 0; r < 16; ++r) {
            int R = (r & 3) + 8 * (r >> 2) + 4 * hi;
            s0[r] = (kv0 + R > qg) ? -1e30f : s0[r];
            s1[r] = (kv0 + 32 + R > qg) ? -1e30f : s1[r];
          }
        }
        float cm = -1e30f;
#pragma unroll
        for (int r = 0; r < 16; ++r) cm = fmaxf(cm, fmaxf(s0[r], s1[r]));
        cm = fmaxf(cm, __shfl_xor(cm, 32));
        float mn = fmaxf(m[qt], cm);
        float fsc = fexp2(m[qt] - mn);
        m[qt] = mn;
        float ssum = 0.0f;
#pragma unroll
        for (int r = 0; r < 16; ++r) {
          s0[r] = fexp2(s0[r] - mn);
          s1[r] = fexp2(s1[r] - mn);
          ssum += s0[r] + s1[r];
        }
        ssum += __shfl_xor(ssum, 32);
        l[qt] = l[qt] * fsc + ssum;
#pragma unroll
        for (int dt = 0; dt < 2; ++dt)
#pragma unroll
          for (int i = 0; i < 16; ++i) o[dt][qt][i] *= fsc;
        // pack P->bf16 and lane-pair exchange -> B-fragments (k = kv = ks*16+hi*8+j)
#pragma unroll
        for (int sub = 0; sub < 2; ++sub) {
          u32 a0, a1, a2, a3, a4, a5, a6, a7;
          if (sub == 0) {
            a0 = pkbf(s0[0], s0[1]);  a1 = pkbf(s0[2], s0[3]);
            a2 = pkbf(s0[4], s0[5]);  a3 = pkbf(s0[6], s0[7]);
            a4 = pkbf(s0[8], s0[9]);  a5 = pkbf(s0[10], s0[11]);
            a6 = pkbf(s0[12], s0[13]); a7 = pkbf(s0[14], s0[15]);
          } else {
            a0 = pkbf(s1[0], s1[1]);  a1 = pkbf(s1[2], s1[3]);
            a2 = pkbf(s1[4], s1[5]);  a3 = pkbf(s1[6], s1[7]);
            a4 = pkbf(s1[8], s1[9]);  a5 = pkbf(s1[10], s1[11]);
            a6 = pkbf(s1[12], s1[13]); a7 = pkbf(s1[14], s1[15]);
          }
          u32 x0 = __shfl_xor(hi ? a0 : a2, 32);
          u32 x1 = __shfl_xor(hi ? a1 : a3, 32);
          u32 x2 = __shfl_xor(hi ? a4 : a6, 32);
          u32 x3 = __shfl_xor(hi ? a5 : a7, 32);
          u32x4 w0, w1;
          w0[0] = hi ? x0 : a0; w0[1] = hi ? x1 : a1;
          w0[2] = hi ? a2 : x0; w0[3] = hi ? a3 : x1;
          w1[0] = hi ? x2 : a4; w1[1] = hi ? x3 : a5;
          w1[2] = hi ? a6 : x2; w1[3] = hi ? a7 : x3;
          pb[qt][sub * 2 + 0] = __builtin_bit_cast(bf16x8, w0);
          pb[qt][sub * 2 + 1] = __builtin_bit_cast(bf16x8, w1);
        }
      }
      // PV: O^T[d][q] += V^T[d][kv] * P^T[kv][q]
#pragma unroll
      for (int dt = 0; dt < 2; ++dt) {
        int r = dt * 32 + ln;
        u32 rs = (u32)((r & 7) << 4);
#pragma unroll
        for (int ks = 0; ks < 4; ++ks) {
          bf16x8 vfk = __builtin_bit_cast(bf16x8,
              *(const ushort8*)(Vc + r * 128 + (u32)((ks * 32 + hi * 16) ^ rs)));
#pragma unroll
          for (int qt = 0; qt < 2; ++qt)
            o[dt][qt] = __builtin_amdgcn_mfma_f32_32x32x16_bf16(vfk, pb[qt][ks], o[dt][qt], 0, 0, 0);
        }
      }
    }
    __syncthreads();
  }

  // epilogue: normalize, transpose O^T -> O through per-wave LDS, coalesced store
  __syncthreads();
  char* Wb = (char*)smem[wave];  // 8KB per wave
#pragma unroll
  for (int qt = 0; qt < 2; ++qt) {
    float inv = 1.0f / l[qt];
    int q = qt * 32 + ln;
    u32 rs = (u32)((q & 7) << 4);
#pragma unroll
    for (int dt = 0; dt < 2; ++dt)
#pragma unroll
      for (int p = 0; p < 8; ++p) {
        u32 w = pkbf(o[dt][qt][2 * p] * inv, o[dt][qt][2 * p + 1] * inv);
        int d = dt * 32 + ((2 * p) & 3) + 8 * (p >> 1) + 4 * hi;
        *(u32*)(Wb + ((u32)(q * 128 + d * 2) ^ rs)) = w;
      }
  }
#pragma unroll
  for (int j = 0; j < 8; ++j) {
    int idx = j * 64 + lane;
    int row = idx >> 3, sp = idx & 7;
    ushort8 v = *(const ushort8*)(Wb + row * 128 + (u32)((sp * 16) ^ ((row & 7) << 4)));
    *(ushort8*)(Ob + (bb * T_ + qw0 + row) * C_ + hh * 64 + sp * 8) = v;
  }
}

// ---------------- launch ----------------
extern "C" void kernel_launch(void* const* d_in, const int* in_sizes, int n_in,
                              void* d_out, int out_size, void* d_ws, size_t ws_size,
                              hipStream_t stream) {
  const float* x = (const float*)d_in[0];
  const float* w_qkv = (const float*)d_in[1];
  const float* w_proj = (const float*)d_in[2];
  const float* b_proj = (const float*)d_in[3];
  float* out = (float*)d_out;

  char* ws = (char*)d_ws;
  u16* xb = (u16*)(ws);                               // 16 MB  [M][C] bf16
  u16* wqT = (u16*)(ws + 16777216);                   // 6 MB   [3C][C] bf16
  u16* wpT = (u16*)(ws + 16777216 + 6291456);         // 2 MB   [C][C] bf16
  u16* Qb = (u16*)(ws + 25165824);                    // 16 MB  [B*H][T][D]
  u16* Kb = (u16*)(ws + 25165824 + 16777216);         // 16 MB  [B*H][T][D]
  u16* Vt = (u16*)(ws + 25165824 + 2 * 16777216);     // 16 MB  [B*H][D][T] (transposed)
  u16* Ob = xb;  // reuse x's bf16 buffer

  cast_kernel<<<(M_ * C_ / 4 + 255) / 256, 256, 0, stream>>>(x, xb, M_ * C_ / 4);
  dim3 tb(32, 8);
  transpose_cast_kernel<<<dim3(3 * C_ / 32, C_ / 32), tb, 0, stream>>>(w_qkv, wqT, C_, 3 * C_);
  transpose_cast_kernel<<<dim3(C_ / 32, C_ / 32), tb, 0, stream>>>(w_proj, wpT, C_, C_);

  gemm_bt<0><<<dim3(3 * C_ / 128, M_ / 128), 256, 0, stream>>>(
      xb, wqT, Qb, Kb, Vt, nullptr, nullptr);

  attn_kernel<<<dim3(T_ / 256, B_ * H_), 256, 0, stream>>>(Qb, Kb, Vt, Ob);

  gemm_bt<1><<<dim3(C_ / 128, M_ / 128), 256, 0, stream>>>(
      Ob, wpT, nullptr, nullptr, nullptr, out, b_proj);
}

// Round 4
// 280.575 us; speedup vs baseline: 2.0341x; 1.0090x over previous
//
#include <hip/hip_runtime.h>

typedef unsigned short u16;
typedef unsigned int u32;
typedef __attribute__((ext_vector_type(8))) __bf16 bf16x8;
typedef __attribute__((ext_vector_type(4))) float f32x4;
typedef __attribute__((ext_vector_type(16))) float f32x16;
typedef __attribute__((ext_vector_type(8))) unsigned short ushort8;
typedef __attribute__((ext_vector_type(4))) unsigned short ushort4v;
typedef __attribute__((ext_vector_type(4))) unsigned int u32x4;
typedef __attribute__((ext_vector_type(4))) float float4v;

#define B_ 4
#define T_ 2048
#define C_ 1024
#define H_ 16
#define D_ 64
#define M_ (B_ * T_)

union ABUn { ushort8 u; bf16x8 b; };

__device__ __forceinline__ u16 f2bf(float f) {
  u32 u = __builtin_bit_cast(u32, f);
  u32 r = u + 0x7fffu + ((u >> 16) & 1u);
  return (u16)(r >> 16);
}

__device__ __forceinline__ float fexp2(float x) {
  float r; asm("v_exp_f32 %0, %1" : "=v"(r) : "v"(x)); return r;
}

__device__ __forceinline__ u32 pkbf(float lo, float hi_) {
  u32 r; asm("v_cvt_pk_bf16_f32 %0, %1, %2" : "=v"(r) : "v"(lo), "v"(hi_)); return r;
}

__device__ __forceinline__ void gl16(const u16* g, u16* l) {
  __builtin_amdgcn_global_load_lds((const __attribute__((address_space(1))) void*)g,
                                   (__attribute__((address_space(3))) void*)l, 16, 0, 0);
}

// ---------------- prep: cast x to bf16 ----------------
__global__ void cast_kernel(const float* __restrict__ in, u16* __restrict__ out, int n4) {
  int i = blockIdx.x * blockDim.x + threadIdx.x;
  if (i >= n4) return;
  float4v v = ((const float4v*)in)[i];
  ushort4v o;
  o[0] = f2bf(v[0]); o[1] = f2bf(v[1]); o[2] = f2bf(v[2]); o[3] = f2bf(v[3]);
  ((ushort4v*)out)[i] = o;
}

// ---------------- prep: transpose + cast weights ----------------
__global__ void transpose_cast_kernel(const float* __restrict__ src, u16* __restrict__ dst,
                                      int Kd, int Nd) {
  __shared__ float tile[32][33];
  int n0 = blockIdx.x * 32, k0 = blockIdx.y * 32;
  int tx = threadIdx.x, ty = threadIdx.y;  // blockDim (32,8)
#pragma unroll
  for (int i = 0; i < 32; i += 8)
    tile[ty + i][tx] = src[(k0 + ty + i) * Nd + n0 + tx];
  __syncthreads();
#pragma unroll
  for (int i = 0; i < 32; i += 8)
    dst[(n0 + ty + i) * Kd + k0 + tx] = f2bf(tile[tx][ty + i]);
}

// ---------------- GEMM: A [M][1024] bf16, Bt [N][1024] bf16 ----------------
// m97 structure: global_load_lds width-16 staging (linear LDS dest,
// pre-swizzled global source so swizzled ds_read_b128 is conflict-free).
// EPI 0: scatter into Q (scaled 0.125*log2e) / K [bh][t][d]; V transposed [bh][d][T]
// EPI 1: Out[m][n] = acc + bias[n]  (f32)
template <int EPI>
__global__ __launch_bounds__(256, 2) void gemm_bt(
    const u16* __restrict__ A, const u16* __restrict__ Bt,
    u16* __restrict__ Qb, u16* __restrict__ Kb, u16* __restrict__ Vb,
    float* __restrict__ Out, const float* __restrict__ bias) {
  __shared__ u16 As[128 * 64];
  __shared__ u16 Bs[128 * 64];
  const int tid = threadIdx.x;
  const int lane = tid & 63, wave = tid >> 6;
  const int wm = wave >> 1, wn = wave & 1;
  const int lg = lane >> 4, lr = lane & 15;
  const int m0 = blockIdx.y * 128, n0 = blockIdx.x * 128;

  f32x4 acc[4][4];
  const f32x4 zero = {0.0f, 0.0f, 0.0f, 0.0f};
#pragma unroll
  for (int mi = 0; mi < 4; ++mi)
#pragma unroll
    for (int ni = 0; ni < 4; ++ni) acc[mi][ni] = zero;

  const u16* Abase = A + m0 * 1024;
  const u16* Bbase = Bt + n0 * 1024;
  int aoff[4];
#pragma unroll
  for (int j = 0; j < 4; ++j) {
    int s = wave * 256 + j * 64 + lane;
    int row = s >> 3, sp = s & 7;
    aoff[j] = row * 1024 + (sp ^ (row & 7)) * 8;
  }
  char* AsB = (char*)As;
  char* BsB = (char*)Bs;

  for (int k0 = 0; k0 < 1024; k0 += 64) {
#pragma unroll
    for (int j = 0; j < 4; ++j) {
      u16* ldst_a = &As[(wave * 256 + j * 64) * 8];
      u16* ldst_b = &Bs[(wave * 256 + j * 64) * 8];
      gl16(Abase + aoff[j] + k0, ldst_a);
      gl16(Bbase + aoff[j] + k0, ldst_b);
    }
    __syncthreads();  // drains vmcnt -> LDS tiles ready
#pragma unroll
    for (int kk = 0; kk < 2; ++kk) {
      bf16x8 am[4], bn[4];
#pragma unroll
      for (int mi = 0; mi < 4; ++mi) {
        int row = wm * 64 + mi * 16 + lr;
        ABUn u;
        u.u = *(const ushort8*)(AsB + ((u32)(row * 128 + ((kk * 64 + lg * 16) ^ ((row & 7) << 4)))));
        am[mi] = u.b;
      }
#pragma unroll
      for (int ni = 0; ni < 4; ++ni) {
        int row = wn * 64 + ni * 16 + lr;
        ABUn u;
        u.u = *(const ushort8*)(BsB + ((u32)(row * 128 + ((kk * 64 + lg * 16) ^ ((row & 7) << 4)))));
        bn[ni] = u.b;
      }
#pragma unroll
      for (int mi = 0; mi < 4; ++mi)
#pragma unroll
        for (int ni = 0; ni < 4; ++ni)
          acc[mi][ni] = __builtin_amdgcn_mfma_f32_16x16x32_bf16(am[mi], bn[ni], acc[mi][ni], 0, 0, 0);
    }
    __syncthreads();
  }

#pragma unroll
  for (int mi = 0; mi < 4; ++mi)
#pragma unroll
    for (int ni = 0; ni < 4; ++ni) {
      int m = m0 + wm * 64 + mi * 16 + lg * 4;  // base t (r adds 0..3)
      int n = n0 + wn * 64 + ni * 16 + lr;
      if (EPI == 0) {
        int part = n >> 10, c = n & 1023;
        int h = c >> 6, d = c & 63;
        int b = m >> 11, t = m & 2047;
        if (part == 2) {
          ushort4v pv;
#pragma unroll
          for (int r = 0; r < 4; ++r) pv[r] = f2bf(acc[mi][ni][r]);
          *(ushort4v*)&Vb[((b * H_ + h) * D_ + d) * T_ + t] = pv;
        } else {
#pragma unroll
          for (int r = 0; r < 4; ++r) {
            float v = acc[mi][ni][r];
            if (part == 0)
              Qb[((b * H_ + h) * T_ + t + r) * D_ + d] = f2bf(v * 0.18033688f);  // 0.125*log2(e)
            else
              Kb[((b * H_ + h) * T_ + t + r) * D_ + d] = f2bf(v);
          }
        }
      } else {
#pragma unroll
        for (int r = 0; r < 4; ++r)
          Out[(m + r) * 1024 + n] = acc[mi][ni][r] + bias[n];
      }
    }
}

// ---------------- flash attention v3 ----------------
// 4 waves x 32 q-rows = 128 q/block; grid 16x64 = 1024 blocks (4/CU).
// KVBLK=64, swapped QK^T, double-buffered LDS K + V^T via global_load_lds.
__global__ __launch_bounds__(256, 4) void attn_kernel(
    const u16* __restrict__ Qb, const u16* __restrict__ Kb,
    const u16* __restrict__ Vt, u16* __restrict__ Ob) {
  __shared__ u16 smem[4][4096];  // [0..1]=K dbuf, [2..3]=V^T dbuf; reused as epi scratch
  const int bh = blockIdx.y;
  const int q0 = (15 - (int)blockIdx.x) * 128;  // heavy blocks first
  const int tid = threadIdx.x;
  const int lane = tid & 63, wave = tid >> 6;
  const int hi = lane >> 5, ln = lane & 31;
  const int qw0 = q0 + wave * 32;
  const int hh = bh & (H_ - 1), bb = bh >> 4;

  const u16* Qh = Qb + bh * (T_ * D_);
  const u16* Kh = Kb + bh * (T_ * D_);
  const u16* Vh = Vt + bh * (T_ * D_);

  // Q B-fragments: lane = q-col ln; k = d = ks*16 + hi*8 + j
  bf16x8 qf[4];
  {
    const u16* qr = Qh + (qw0 + ln) * 64 + hi * 8;
#pragma unroll
    for (int ks = 0; ks < 4; ++ks)
      qf[ks] = __builtin_bit_cast(bf16x8, *(const ushort8*)(qr + ks * 16));
  }

  f32x16 o[2];
#pragma unroll
  for (int dt = 0; dt < 2; ++dt)
#pragma unroll
    for (int i = 0; i < 16; ++i) o[dt][i] = 0.0f;
  float m = -1e30f, l = 0.0f;

  const int nchunk = q0 / 64 + 2;
  const int slot0 = wave * 128;  // this wave's staging slots (x2 instrs of 64)

  // prologue: stage chunk 0 into buf 0
#pragma unroll
  for (int j = 0; j < 2; ++j) {
    int slot = slot0 + j * 64 + lane;
    int r = slot >> 3, sp = slot & 7;
    int sl = sp ^ (r & 7);
    gl16(Kh + r * 64 + sl * 8, &smem[0][(slot0 + j * 64) * 8]);
    gl16(Vh + r * 2048 + sl * 8, &smem[2][(slot0 + j * 64) * 8]);
  }
  __syncthreads();

  for (int ch = 0; ch < nchunk; ++ch) {
    const int kv0 = ch * 64;
    const int cur = ch & 1;
    if (ch + 1 < nchunk) {  // async prefetch next chunk into other buffer
      const int kn = kv0 + 64;
#pragma unroll
      for (int j = 0; j < 2; ++j) {
        int slot = slot0 + j * 64 + lane;
        int r = slot >> 3, sp = slot & 7;
        int sl = sp ^ (r & 7);
        gl16(Kh + (kn + r) * 64 + sl * 8, &smem[cur ^ 1][(slot0 + j * 64) * 8]);
        gl16(Vh + r * 2048 + kn + sl * 8, &smem[2 + (cur ^ 1)][(slot0 + j * 64) * 8]);
      }
    }
    if (kv0 <= qw0 + 31) {  // wave-uniform: skip fully-masked chunks
      const char* Kc = (const char*)smem[cur];
      const char* Vc = (const char*)smem[2 + cur];
      f32x16 s0, s1;
#pragma unroll
      for (int i = 0; i < 16; ++i) { s0[i] = 0.0f; s1[i] = 0.0f; }
      __builtin_amdgcn_s_setprio(1);
#pragma unroll
      for (int ks = 0; ks < 4; ++ks) {
        int r0 = ln, r1 = 32 + ln;
        bf16x8 kf0 = __builtin_bit_cast(bf16x8,
            *(const ushort8*)(Kc + r0 * 128 + (u32)((ks * 32 + hi * 16) ^ ((r0 & 7) << 4))));
        bf16x8 kf1 = __builtin_bit_cast(bf16x8,
            *(const ushort8*)(Kc + r1 * 128 + (u32)((ks * 32 + hi * 16) ^ ((r1 & 7) << 4))));
        s0 = __builtin_amdgcn_mfma_f32_32x32x16_bf16(kf0, qf[ks], s0, 0, 0, 0);
        s1 = __builtin_amdgcn_mfma_f32_32x32x16_bf16(kf1, qf[ks], s1, 0, 0, 0);
      }
      __builtin_amdgcn_s_setprio(0);

      const int qg = qw0 + ln;
      if ((kv0 + 63) > qw0) {  // partial chunk: causal mask
#pragma unroll
        for (int r = 0; r < 16; ++r) {
          int R = (r & 3) + 8 * (r >> 2) + 4 * hi;
          s0[r] = (kv0 + R > qg) ? -1e30f : s0[r];
          s1[r] = (kv0 + 32 + R > qg) ? -1e30f : s1[r];
        }
      }
      // tree max
      float mx[8];
#pragma unroll
      for (int i = 0; i < 8; ++i)
        mx[i] = fmaxf(fmaxf(s0[i], s0[i + 8]), fmaxf(s1[i], s1[i + 8]));
#pragma unroll
      for (int i = 0; i < 4; ++i) mx[i] = fmaxf(mx[i], mx[i + 4]);
      float cm = fmaxf(fmaxf(mx[0], mx[1]), fmaxf(mx[2], mx[3]));
      cm = fmaxf(cm, __shfl_xor(cm, 32));
      float mn = fmaxf(m, cm);
      float fsc = fexp2(m - mn);
      m = mn;
#pragma unroll
      for (int r = 0; r < 16; ++r) {
        s0[r] = fexp2(s0[r] - mn);
        s1[r] = fexp2(s1[r] - mn);
      }
      // tree sum
      float sm[8];
#pragma unroll
      for (int i = 0; i < 8; ++i) sm[i] = (s0[i] + s0[i + 8]) + (s1[i] + s1[i + 8]);
#pragma unroll
      for (int i = 0; i < 4; ++i) sm[i] += sm[i + 4];
      float ssum = (sm[0] + sm[1]) + (sm[2] + sm[3]);
      ssum += __shfl_xor(ssum, 32);
      l = l * fsc + ssum;
#pragma unroll
      for (int dt = 0; dt < 2; ++dt)
#pragma unroll
        for (int i = 0; i < 16; ++i) o[dt][i] *= fsc;

      // pack P->bf16 and lane-pair exchange -> B-fragments (k = kv = ks*16+hi*8+j)
      bf16x8 pb[4];
#pragma unroll
      for (int sub = 0; sub < 2; ++sub) {
        u32 a0, a1, a2, a3, a4, a5, a6, a7;
        if (sub == 0) {
          a0 = pkbf(s0[0], s0[1]);  a1 = pkbf(s0[2], s0[3]);
          a2 = pkbf(s0[4], s0[5]);  a3 = pkbf(s0[6], s0[7]);
          a4 = pkbf(s0[8], s0[9]);  a5 = pkbf(s0[10], s0[11]);
          a6 = pkbf(s0[12], s0[13]); a7 = pkbf(s0[14], s0[15]);
        } else {
          a0 = pkbf(s1[0], s1[1]);  a1 = pkbf(s1[2], s1[3]);
          a2 = pkbf(s1[4], s1[5]);  a3 = pkbf(s1[6], s1[7]);
          a4 = pkbf(s1[8], s1[9]);  a5 = pkbf(s1[10], s1[11]);
          a6 = pkbf(s1[12], s1[13]); a7 = pkbf(s1[14], s1[15]);
        }
        u32 x0 = __shfl_xor(hi ? a0 : a2, 32);
        u32 x1 = __shfl_xor(hi ? a1 : a3, 32);
        u32 x2 = __shfl_xor(hi ? a4 : a6, 32);
        u32 x3 = __shfl_xor(hi ? a5 : a7, 32);
        u32x4 w0, w1;
        w0[0] = hi ? x0 : a0; w0[1] = hi ? x1 : a1;
        w0[2] = hi ? a2 : x0; w0[3] = hi ? a3 : x1;
        w1[0] = hi ? x2 : a4; w1[1] = hi ? x3 : a5;
        w1[2] = hi ? a6 : x2; w1[3] = hi ? a7 : x3;
        pb[sub * 2 + 0] = __builtin_bit_cast(bf16x8, w0);
        pb[sub * 2 + 1] = __builtin_bit_cast(bf16x8, w1);
      }
      // PV: O^T[d][q] += V^T[d][kv] * P^T[kv][q]
      __builtin_amdgcn_s_setprio(1);
#pragma unroll
      for (int dt = 0; dt < 2; ++dt) {
        int r = dt * 32 + ln;
        u32 rs = (u32)((r & 7) << 4);
#pragma unroll
        for (int ks = 0; ks < 4; ++ks) {
          bf16x8 vfk = __builtin_bit_cast(bf16x8,
              *(const ushort8*)(Vc + r * 128 + (u32)((ks * 32 + hi * 16) ^ rs)));
          o[dt] = __builtin_amdgcn_mfma_f32_32x32x16_bf16(vfk, pb[ks], o[dt], 0, 0, 0);
        }
      }
      __builtin_amdgcn_s_setprio(0);
    }
    __syncthreads();
  }

  // epilogue: normalize, transpose O^T -> O through per-wave LDS, coalesced store
  __syncthreads();
  char* Wb = (char*)smem[wave];  // 8KB per wave (uses first 4KB)
  {
    float inv = 1.0f / l;
    int q = ln;
    u32 rs = (u32)((q & 7) << 4);
#pragma unroll
    for (int dt = 0; dt < 2; ++dt)
#pragma unroll
      for (int p = 0; p < 8; ++p) {
        u32 w = pkbf(o[dt][2 * p] * inv, o[dt][2 * p + 1] * inv);
        int d = dt * 32 + ((2 * p) & 3) + 8 * (p >> 1) + 4 * hi;
        *(u32*)(Wb + ((u32)(q * 128 + d * 2) ^ rs)) = w;
      }
  }
#pragma unroll
  for (int j = 0; j < 4; ++j) {
    int idx = j * 64 + lane;
    int row = idx >> 3, sp = idx & 7;
    ushort8 v = *(const ushort8*)(Wb + row * 128 + (u32)((sp * 16) ^ ((row & 7) << 4)));
    *(ushort8*)(Ob + (bb * T_ + qw0 + row) * C_ + hh * 64 + sp * 8) = v;
  }
}

// ---------------- launch ----------------
extern "C" void kernel_launch(void* const* d_in, const int* in_sizes, int n_in,
                              void* d_out, int out_size, void* d_ws, size_t ws_size,
                              hipStream_t stream) {
  const float* x = (const float*)d_in[0];
  const float* w_qkv = (const float*)d_in[1];
  const float* w_proj = (const float*)d_in[2];
  const float* b_proj = (const float*)d_in[3];
  float* out = (float*)d_out;

  char* ws = (char*)d_ws;
  u16* xb = (u16*)(ws);                               // 16 MB  [M][C] bf16
  u16* wqT = (u16*)(ws + 16777216);                   // 6 MB   [3C][C] bf16
  u16* wpT = (u16*)(ws + 16777216 + 6291456);         // 2 MB   [C][C] bf16
  u16* Qb = (u16*)(ws + 25165824);                    // 16 MB  [B*H][T][D]
  u16* Kb = (u16*)(ws + 25165824 + 16777216);         // 16 MB  [B*H][T][D]
  u16* Vt = (u16*)(ws + 25165824 + 2 * 16777216);     // 16 MB  [B*H][D][T] (transposed)
  u16* Ob = xb;  // reuse x's bf16 buffer

  cast_kernel<<<(M_ * C_ / 4 + 255) / 256, 256, 0, stream>>>(x, xb, M_ * C_ / 4);
  dim3 tb(32, 8);
  transpose_cast_kernel<<<dim3(3 * C_ / 32, C_ / 32), tb, 0, stream>>>(w_qkv, wqT, C_, 3 * C_);
  transpose_cast_kernel<<<dim3(C_ / 32, C_ / 32), tb, 0, stream>>>(w_proj, wpT, C_, C_);

  gemm_bt<0><<<dim3(3 * C_ / 128, M_ / 128), 256, 0, stream>>>(
      xb, wqT, Qb, Kb, Vt, nullptr, nullptr);

  attn_kernel<<<dim3(T_ / 128, B_ * H_), 256, 0, stream>>>(Qb, Kb, Vt, Ob);

  gemm_bt<1><<<dim3(C_ / 128, M_ / 128), 256, 0, stream>>>(
      Ob, wpT, nullptr, nullptr, nullptr, out, b_proj);
}

// Round 7
// 249.965 us; speedup vs baseline: 2.2832x; 1.1225x over previous
//
#include <hip/hip_runtime.h>

typedef unsigned short u16;
typedef unsigned int u32;
typedef __attribute__((ext_vector_type(8))) __bf16 bf16x8;
typedef __attribute__((ext_vector_type(4))) float f32x4;
typedef __attribute__((ext_vector_type(16))) float f32x16;
typedef __attribute__((ext_vector_type(8))) unsigned short ushort8;
typedef __attribute__((ext_vector_type(4))) unsigned short ushort4v;
typedef __attribute__((ext_vector_type(4))) unsigned int u32x4;
typedef __attribute__((ext_vector_type(4))) float float4v;

#define B_ 4
#define T_ 2048
#define C_ 1024
#define H_ 16
#define D_ 64
#define M_ (B_ * T_)

union ABUn { ushort8 u; bf16x8 b; };

__device__ __forceinline__ u16 f2bf(float f) {
  u32 u = __builtin_bit_cast(u32, f);
  u32 r = u + 0x7fffu + ((u >> 16) & 1u);
  return (u16)(r >> 16);
}

__device__ __forceinline__ float fexp2(float x) {
  float r; asm("v_exp_f32 %0, %1" : "=v"(r) : "v"(x)); return r;
}

__device__ __forceinline__ u32 pkbf(float lo, float hi_) {
  u32 r; asm("v_cvt_pk_bf16_f32 %0, %1, %2" : "=v"(r) : "v"(lo), "v"(hi_)); return r;
}

__device__ __forceinline__ void gl16(const u16* g, u16* l) {
  __builtin_amdgcn_global_load_lds((const __attribute__((address_space(1))) void*)g,
                                   (__attribute__((address_space(3))) void*)l, 16, 0, 0);
}

// ---------------- prep: cast x to bf16 ----------------
__global__ void cast_kernel(const float* __restrict__ in, u16* __restrict__ out, int n4) {
  int i = blockIdx.x * blockDim.x + threadIdx.x;
  if (i >= n4) return;
  float4v v = ((const float4v*)in)[i];
  ushort4v o;
  o[0] = f2bf(v[0]); o[1] = f2bf(v[1]); o[2] = f2bf(v[2]); o[3] = f2bf(v[3]);
  ((ushort4v*)out)[i] = o;
}

// ---------------- prep: transpose + cast weights ----------------
__global__ void transpose_cast_kernel(const float* __restrict__ src, u16* __restrict__ dst,
                                      int Kd, int Nd) {
  __shared__ float tile[32][33];
  int n0 = blockIdx.x * 32, k0 = blockIdx.y * 32;
  int tx = threadIdx.x, ty = threadIdx.y;  // blockDim (32,8)
#pragma unroll
  for (int i = 0; i < 32; i += 8)
    tile[ty + i][tx] = src[(k0 + ty + i) * Nd + n0 + tx];
  __syncthreads();
#pragma unroll
  for (int i = 0; i < 32; i += 8)
    dst[(n0 + ty + i) * Kd + k0 + tx] = f2bf(tile[tx][ty + i]);
}

// ---------------- GEMM: A [M][1024] bf16, Bt [N][1024] bf16 ----------------
// m97 structure: global_load_lds width-16 staging (linear LDS dest,
// pre-swizzled global source so swizzled ds_read_b128 is conflict-free).
// EPI 0: scatter into Q (scaled 0.125*log2e) / K [bh][t][d]; V transposed [bh][d][T]
// EPI 1: Out[m][n] = acc + bias[n]  (f32)
template <int EPI>
__global__ __launch_bounds__(256, 2) void gemm_bt(
    const u16* __restrict__ A, const u16* __restrict__ Bt,
    u16* __restrict__ Qb, u16* __restrict__ Kb, u16* __restrict__ Vb,
    float* __restrict__ Out, const float* __restrict__ bias) {
  __shared__ u16 As[128 * 64];
  __shared__ u16 Bs[128 * 64];
  const int tid = threadIdx.x;
  const int lane = tid & 63, wave = tid >> 6;
  const int wm = wave >> 1, wn = wave & 1;
  const int lg = lane >> 4, lr = lane & 15;
  const int m0 = blockIdx.y * 128, n0 = blockIdx.x * 128;

  f32x4 acc[4][4];
  const f32x4 zero = {0.0f, 0.0f, 0.0f, 0.0f};
#pragma unroll
  for (int mi = 0; mi < 4; ++mi)
#pragma unroll
    for (int ni = 0; ni < 4; ++ni) acc[mi][ni] = zero;

  const u16* Abase = A + m0 * 1024;
  const u16* Bbase = Bt + n0 * 1024;
  int aoff[4];
#pragma unroll
  for (int j = 0; j < 4; ++j) {
    int s = wave * 256 + j * 64 + lane;
    int row = s >> 3, sp = s & 7;
    aoff[j] = row * 1024 + (sp ^ (row & 7)) * 8;
  }
  char* AsB = (char*)As;
  char* BsB = (char*)Bs;

  for (int k0 = 0; k0 < 1024; k0 += 64) {
#pragma unroll
    for (int j = 0; j < 4; ++j) {
      u16* ldst_a = &As[(wave * 256 + j * 64) * 8];
      u16* ldst_b = &Bs[(wave * 256 + j * 64) * 8];
      gl16(Abase + aoff[j] + k0, ldst_a);
      gl16(Bbase + aoff[j] + k0, ldst_b);
    }
    __syncthreads();  // drains vmcnt -> LDS tiles ready
#pragma unroll
    for (int kk = 0; kk < 2; ++kk) {
      bf16x8 am[4], bn[4];
#pragma unroll
      for (int mi = 0; mi < 4; ++mi) {
        int row = wm * 64 + mi * 16 + lr;
        ABUn u;
        u.u = *(const ushort8*)(AsB + ((u32)(row * 128 + ((kk * 64 + lg * 16) ^ ((row & 7) << 4)))));
        am[mi] = u.b;
      }
#pragma unroll
      for (int ni = 0; ni < 4; ++ni) {
        int row = wn * 64 + ni * 16 + lr;
        ABUn u;
        u.u = *(const ushort8*)(BsB + ((u32)(row * 128 + ((kk * 64 + lg * 16) ^ ((row & 7) << 4)))));
        bn[ni] = u.b;
      }
#pragma unroll
      for (int mi = 0; mi < 4; ++mi)
#pragma unroll
        for (int ni = 0; ni < 4; ++ni)
          acc[mi][ni] = __builtin_amdgcn_mfma_f32_16x16x32_bf16(am[mi], bn[ni], acc[mi][ni], 0, 0, 0);
    }
    __syncthreads();
  }

#pragma unroll
  for (int mi = 0; mi < 4; ++mi)
#pragma unroll
    for (int ni = 0; ni < 4; ++ni) {
      int m = m0 + wm * 64 + mi * 16 + lg * 4;  // base t (r adds 0..3)
      int n = n0 + wn * 64 + ni * 16 + lr;
      if (EPI == 0) {
        int part = n >> 10, c = n & 1023;
        int h = c >> 6, d = c & 63;
        int b = m >> 11, t = m & 2047;
        if (part == 2) {
          ushort4v pv;
#pragma unroll
          for (int r = 0; r < 4; ++r) pv[r] = f2bf(acc[mi][ni][r]);
          *(ushort4v*)&Vb[((b * H_ + h) * D_ + d) * T_ + t] = pv;
        } else {
#pragma unroll
          for (int r = 0; r < 4; ++r) {
            float v = acc[mi][ni][r];
            if (part == 0)
              Qb[((b * H_ + h) * T_ + t + r) * D_ + d] = f2bf(v * 0.18033688f);  // 0.125*log2(e)
            else
              Kb[((b * H_ + h) * T_ + t + r) * D_ + d] = f2bf(v);
          }
        }
      } else {
#pragma unroll
        for (int r = 0; r < 4; ++r)
          Out[(m + r) * 1024 + n] = acc[mi][ni][r] + bias[n];
      }
    }
}

// ---------------- flash attention v4: causal-paired, balanced ----------------
// grid (8, 64) = 512 blocks, uniform work: block bx processes q-tiles
// bx*128 and 1920-bx*128 (34 staged chunks each block). 4 waves x 32 q-rows.
// KVBLK=64, swapped QK^T, double-buffered LDS K + V^T via global_load_lds.
__global__ __launch_bounds__(256, 4) void attn_kernel(
    const u16* __restrict__ Qb, const u16* __restrict__ Kb,
    const u16* __restrict__ Vt, u16* __restrict__ Ob) {
  __shared__ u16 smem[4][4096];  // [0..1]=K dbuf, [2..3]=V^T dbuf; reused as epi scratch
  const int bh = blockIdx.y;
  const int tid = threadIdx.x;
  const int lane = tid & 63, wave = tid >> 6;
  const int hi = lane >> 5, ln = lane & 31;
  const int hh = bh & (H_ - 1), bb = bh >> 4;

  const u16* Qh = Qb + bh * (T_ * D_);
  const u16* Kh = Kb + bh * (T_ * D_);
  const u16* Vh = Vt + bh * (T_ * D_);
  const int slot0 = wave * 128;

  // precompute this thread's staging slot geometry
  int srow[2], scol[2];
#pragma unroll
  for (int j = 0; j < 2; ++j) {
    int slot = slot0 + j * 64 + lane;
    srow[j] = slot >> 3;
    scol[j] = (slot & 7) ^ (srow[j] & 7);  // pre-swizzled global 16B-chunk
  }

#pragma unroll
  for (int pass = 0; pass < 2; ++pass) {
    const int q0 = pass ? (1920 - (int)blockIdx.x * 128) : ((int)blockIdx.x * 128);
    const int qw0 = q0 + wave * 32;

    // Q B-fragments: lane = q-col ln; k = d = ks*16 + hi*8 + j
    bf16x8 qf[4];
    {
      const u16* qr = Qh + (qw0 + ln) * 64 + hi * 8;
#pragma unroll
      for (int ks = 0; ks < 4; ++ks)
        qf[ks] = __builtin_bit_cast(bf16x8, *(const ushort8*)(qr + ks * 16));
    }

    f32x16 o[2];
#pragma unroll
    for (int dt = 0; dt < 2; ++dt)
#pragma unroll
      for (int i = 0; i < 16; ++i) o[dt][i] = 0.0f;
    float m = -1e30f, l = 0.0f;

    const int nchunk = q0 / 64 + 2;

    __syncthreads();  // smem free (prev pass epilogue done)
    // prologue: stage chunk 0 into buf 0
#pragma unroll
    for (int j = 0; j < 2; ++j) {
      gl16(Kh + srow[j] * 64 + scol[j] * 8, &smem[0][(slot0 + j * 64) * 8]);
      gl16(Vh + srow[j] * 2048 + scol[j] * 8, &smem[2][(slot0 + j * 64) * 8]);
    }
    __syncthreads();

    for (int ch = 0; ch < nchunk; ++ch) {
      const int kv0 = ch * 64;
      const int cur = ch & 1;
      if (ch + 1 < nchunk) {  // async prefetch next chunk into other buffer
        const int kn = kv0 + 64;
#pragma unroll
        for (int j = 0; j < 2; ++j) {
          gl16(Kh + (kn + srow[j]) * 64 + scol[j] * 8, &smem[cur ^ 1][(slot0 + j * 64) * 8]);
          gl16(Vh + srow[j] * 2048 + kn + scol[j] * 8, &smem[2 + (cur ^ 1)][(slot0 + j * 64) * 8]);
        }
      }
      if (kv0 <= qw0 + 31) {  // wave-uniform: skip fully-masked chunks
        const char* Kc = (const char*)smem[cur];
        const char* Vc = (const char*)smem[2 + cur];
        f32x16 s0, s1;
#pragma unroll
        for (int i = 0; i < 16; ++i) { s0[i] = 0.0f; s1[i] = 0.0f; }
        __builtin_amdgcn_s_setprio(1);
#pragma unroll
        for (int ks = 0; ks < 4; ++ks) {
          int r0 = ln, r1 = 32 + ln;
          bf16x8 kf0 = __builtin_bit_cast(bf16x8,
              *(const ushort8*)(Kc + r0 * 128 + (u32)((ks * 32 + hi * 16) ^ ((r0 & 7) << 4))));
          bf16x8 kf1 = __builtin_bit_cast(bf16x8,
              *(const ushort8*)(Kc + r1 * 128 + (u32)((ks * 32 + hi * 16) ^ ((r1 & 7) << 4))));
          s0 = __builtin_amdgcn_mfma_f32_32x32x16_bf16(kf0, qf[ks], s0, 0, 0, 0);
          s1 = __builtin_amdgcn_mfma_f32_32x32x16_bf16(kf1, qf[ks], s1, 0, 0, 0);
        }
        __builtin_amdgcn_s_setprio(0);

        const int qg = qw0 + ln;
        if ((kv0 + 63) > qw0) {  // partial chunk: causal mask
#pragma unroll
          for (int r = 0; r < 16; ++r) {
            int R = (r & 3) + 8 * (r >> 2) + 4 * hi;
            s0[r] = (kv0 + R > qg) ? -1e30f : s0[r];
            s1[r] = (kv0 + 32 + R > qg) ? -1e30f : s1[r];
          }
        }
        // tree max
        float mx[8];
#pragma unroll
        for (int i = 0; i < 8; ++i)
          mx[i] = fmaxf(fmaxf(s0[i], s0[i + 8]), fmaxf(s1[i], s1[i + 8]));
#pragma unroll
        for (int i = 0; i < 4; ++i) mx[i] = fmaxf(mx[i], mx[i + 4]);
        float cm = fmaxf(fmaxf(mx[0], mx[1]), fmaxf(mx[2], mx[3]));
        cm = fmaxf(cm, __shfl_xor(cm, 32));
        float mn = fmaxf(m, cm);
        float fsc = fexp2(m - mn);
        m = mn;
#pragma unroll
        for (int r = 0; r < 16; ++r) {
          s0[r] = fexp2(s0[r] - mn);
          s1[r] = fexp2(s1[r] - mn);
        }
        // tree sum
        float sm[8];
#pragma unroll
        for (int i = 0; i < 8; ++i) sm[i] = (s0[i] + s0[i + 8]) + (s1[i] + s1[i + 8]);
#pragma unroll
        for (int i = 0; i < 4; ++i) sm[i] += sm[i + 4];
        float ssum = (sm[0] + sm[1]) + (sm[2] + sm[3]);
        ssum += __shfl_xor(ssum, 32);
        l = l * fsc + ssum;
#pragma unroll
        for (int dt = 0; dt < 2; ++dt)
#pragma unroll
          for (int i = 0; i < 16; ++i) o[dt][i] *= fsc;

        // pack P->bf16; v_permlane32_swap builds B-fragments in-register
        bf16x8 pb[4];
#pragma unroll
        for (int sub = 0; sub < 2; ++sub) {
          u32 a0, a1, a2, a3, a4, a5, a6, a7;
          if (sub == 0) {
            a0 = pkbf(s0[0], s0[1]);  a1 = pkbf(s0[2], s0[3]);
            a2 = pkbf(s0[4], s0[5]);  a3 = pkbf(s0[6], s0[7]);
            a4 = pkbf(s0[8], s0[9]);  a5 = pkbf(s0[10], s0[11]);
            a6 = pkbf(s0[12], s0[13]); a7 = pkbf(s0[14], s0[15]);
          } else {
            a0 = pkbf(s1[0], s1[1]);  a1 = pkbf(s1[2], s1[3]);
            a2 = pkbf(s1[4], s1[5]);  a3 = pkbf(s1[6], s1[7]);
            a4 = pkbf(s1[8], s1[9]);  a5 = pkbf(s1[10], s1[11]);
            a6 = pkbf(s1[12], s1[13]); a7 = pkbf(s1[14], s1[15]);
          }
          // swap(a_lo_pair): vdst.hi <-> src.lo
          asm volatile("v_permlane32_swap_b32 %0, %1" : "+v"(a0), "+v"(a2));
          asm volatile("v_permlane32_swap_b32 %0, %1" : "+v"(a1), "+v"(a3));
          asm volatile("v_permlane32_swap_b32 %0, %1" : "+v"(a4), "+v"(a6));
          asm volatile("v_permlane32_swap_b32 %0, %1" : "+v"(a5), "+v"(a7));
          u32x4 w0, w1;
          w0[0] = a0; w0[1] = a1; w0[2] = a2; w0[3] = a3;
          w1[0] = a4; w1[1] = a5; w1[2] = a6; w1[3] = a7;
          pb[sub * 2 + 0] = __builtin_bit_cast(bf16x8, w0);
          pb[sub * 2 + 1] = __builtin_bit_cast(bf16x8, w1);
        }
        // PV: O^T[d][q] += V^T[d][kv] * P^T[kv][q]
        __builtin_amdgcn_s_setprio(1);
#pragma unroll
        for (int dt = 0; dt < 2; ++dt) {
          int r = dt * 32 + ln;
          u32 rs = (u32)((r & 7) << 4);
#pragma unroll
          for (int ks = 0; ks < 4; ++ks) {
            bf16x8 vfk = __builtin_bit_cast(bf16x8,
                *(const ushort8*)(Vc + r * 128 + (u32)((ks * 32 + hi * 16) ^ rs)));
            o[dt] = __builtin_amdgcn_mfma_f32_32x32x16_bf16(vfk, pb[ks], o[dt], 0, 0, 0);
          }
        }
        __builtin_amdgcn_s_setprio(0);
      }
      __syncthreads();
    }

    // epilogue: normalize, transpose O^T -> O through per-wave LDS, coalesced store
    __syncthreads();
    char* Wb = (char*)smem[wave];  // 8KB per wave (uses first 4KB)
    {
      float inv = 1.0f / l;
      int q = ln;
      u32 rs = (u32)((q & 7) << 4);
#pragma unroll
      for (int dt = 0; dt < 2; ++dt)
#pragma unroll
        for (int p = 0; p < 8; ++p) {
          u32 w = pkbf(o[dt][2 * p] * inv, o[dt][2 * p + 1] * inv);
          int d = dt * 32 + ((2 * p) & 3) + 8 * (p >> 1) + 4 * hi;
          *(u32*)(Wb + ((u32)(q * 128 + d * 2) ^ rs)) = w;
        }
    }
    asm volatile("s_waitcnt lgkmcnt(0)" ::: "memory");
#pragma unroll
    for (int j = 0; j < 4; ++j) {
      int idx = j * 64 + lane;
      int row = idx >> 3, sp = idx & 7;
      ushort8 v = *(const ushort8*)(Wb + row * 128 + (u32)((sp * 16) ^ ((row & 7) << 4)));
      *(ushort8*)(Ob + (bb * T_ + qw0 + row) * C_ + hh * 64 + sp * 8) = v;
    }
  }
}

// ---------------- launch ----------------
extern "C" void kernel_launch(void* const* d_in, const int* in_sizes, int n_in,
                              void* d_out, int out_size, void* d_ws, size_t ws_size,
                              hipStream_t stream) {
  const float* x = (const float*)d_in[0];
  const float* w_qkv = (const float*)d_in[1];
  const float* w_proj = (const float*)d_in[2];
  const float* b_proj = (const float*)d_in[3];
  float* out = (float*)d_out;

  char* ws = (char*)d_ws;
  u16* xb = (u16*)(ws);                               // 16 MB  [M][C] bf16
  u16* wqT = (u16*)(ws + 16777216);                   // 6 MB   [3C][C] bf16
  u16* wpT = (u16*)(ws + 16777216 + 6291456);         // 2 MB   [C][C] bf16
  u16* Qb = (u16*)(ws + 25165824);                    // 16 MB  [B*H][T][D]
  u16* Kb = (u16*)(ws + 25165824 + 16777216);         // 16 MB  [B*H][T][D]
  u16* Vt = (u16*)(ws + 25165824 + 2 * 16777216);     // 16 MB  [B*H][D][T] (transposed)
  u16* Ob = xb;  // reuse x's bf16 buffer

  cast_kernel<<<(M_ * C_ / 4 + 255) / 256, 256, 0, stream>>>(x, xb, M_ * C_ / 4);
  dim3 tb(32, 8);
  transpose_cast_kernel<<<dim3(3 * C_ / 32, C_ / 32), tb, 0, stream>>>(w_qkv, wqT, C_, 3 * C_);
  transpose_cast_kernel<<<dim3(C_ / 32, C_ / 32), tb, 0, stream>>>(w_proj, wpT, C_, C_);

  gemm_bt<0><<<dim3(3 * C_ / 128, M_ / 128), 256, 0, stream>>>(
      xb, wqT, Qb, Kb, Vt, nullptr, nullptr);

  attn_kernel<<<dim3(T_ / 256, B_ * H_), 256, 0, stream>>>(Qb, Kb, Vt, Ob);

  gemm_bt<1><<<dim3(C_ / 128, M_ / 128), 256, 0, stream>>>(
      Ob, wpT, nullptr, nullptr, nullptr, out, b_proj);
}

// Round 9
// 234.082 us; speedup vs baseline: 2.4381x; 1.0678x over previous
//
#include <hip/hip_runtime.h>

typedef unsigned short u16;
typedef unsigned int u32;
typedef __attribute__((ext_vector_type(8))) __bf16 bf16x8;
typedef __attribute__((ext_vector_type(4))) float f32x4;
typedef __attribute__((ext_vector_type(16))) float f32x16;
typedef __attribute__((ext_vector_type(8))) unsigned short ushort8;
typedef __attribute__((ext_vector_type(4))) unsigned short ushort4v;
typedef __attribute__((ext_vector_type(4))) unsigned int u32x4;
typedef __attribute__((ext_vector_type(4))) float float4v;

#define B_ 4
#define T_ 2048
#define C_ 1024
#define H_ 16
#define D_ 64
#define M_ (B_ * T_)

union ABUn { ushort8 u; bf16x8 b; };

__device__ __forceinline__ u16 f2bf(float f) {
  u32 u = __builtin_bit_cast(u32, f);
  u32 r = u + 0x7fffu + ((u >> 16) & 1u);
  return (u16)(r >> 16);
}

__device__ __forceinline__ float fexp2(float x) {
  float r; asm("v_exp_f32 %0, %1" : "=v"(r) : "v"(x)); return r;
}

__device__ __forceinline__ u32 pkbf(float lo, float hi_) {
  u32 r; asm("v_cvt_pk_bf16_f32 %0, %1, %2" : "=v"(r) : "v"(lo), "v"(hi_)); return r;
}

__device__ __forceinline__ void gl16(const u16* g, u16* l) {
  __builtin_amdgcn_global_load_lds((const __attribute__((address_space(1))) void*)g,
                                   (__attribute__((address_space(3))) void*)l, 16, 0, 0);
}

// ---------------- prep: cast x to bf16 ----------------
__global__ void cast_kernel(const float* __restrict__ in, u16* __restrict__ out, int n4) {
  int i = blockIdx.x * blockDim.x + threadIdx.x;
  if (i >= n4) return;
  float4v v = ((const float4v*)in)[i];
  ushort4v o;
  o[0] = f2bf(v[0]); o[1] = f2bf(v[1]); o[2] = f2bf(v[2]); o[3] = f2bf(v[3]);
  ((ushort4v*)out)[i] = o;
}

// ---------------- prep: transpose + cast weights ----------------
__global__ void transpose_cast_kernel(const float* __restrict__ src, u16* __restrict__ dst,
                                      int Kd, int Nd) {
  __shared__ float tile[32][33];
  int n0 = blockIdx.x * 32, k0 = blockIdx.y * 32;
  int tx = threadIdx.x, ty = threadIdx.y;  // blockDim (32,8)
#pragma unroll
  for (int i = 0; i < 32; i += 8)
    tile[ty + i][tx] = src[(k0 + ty + i) * Nd + n0 + tx];
  __syncthreads();
#pragma unroll
  for (int i = 0; i < 32; i += 8)
    dst[(n0 + ty + i) * Kd + k0 + tx] = f2bf(tile[tx][ty + i]);
}

// ---------------- GEMM: A [M][1024] bf16, Bt [N][1024] bf16 ----------------
// m97 structure: global_load_lds width-16 staging (linear LDS dest,
// pre-swizzled global source so swizzled ds_read_b128 is conflict-free).
// EPI 0: scatter into Q (scaled 0.125*log2e) / K [bh][t][d]; V transposed [bh][d][T]
// EPI 1: Out[m][n] = acc + bias[n]  (f32)
template <int EPI>
__global__ __launch_bounds__(256, 2) void gemm_bt(
    const u16* __restrict__ A, const u16* __restrict__ Bt,
    u16* __restrict__ Qb, u16* __restrict__ Kb, u16* __restrict__ Vb,
    float* __restrict__ Out, const float* __restrict__ bias) {
  __shared__ u16 As[128 * 64];
  __shared__ u16 Bs[128 * 64];
  const int tid = threadIdx.x;
  const int lane = tid & 63, wave = tid >> 6;
  const int wm = wave >> 1, wn = wave & 1;
  const int lg = lane >> 4, lr = lane & 15;
  const int m0 = blockIdx.y * 128, n0 = blockIdx.x * 128;

  f32x4 acc[4][4];
  const f32x4 zero = {0.0f, 0.0f, 0.0f, 0.0f};
#pragma unroll
  for (int mi = 0; mi < 4; ++mi)
#pragma unroll
    for (int ni = 0; ni < 4; ++ni) acc[mi][ni] = zero;

  const u16* Abase = A + m0 * 1024;
  const u16* Bbase = Bt + n0 * 1024;
  int aoff[4];
#pragma unroll
  for (int j = 0; j < 4; ++j) {
    int s = wave * 256 + j * 64 + lane;
    int row = s >> 3, sp = s & 7;
    aoff[j] = row * 1024 + (sp ^ (row & 7)) * 8;
  }
  char* AsB = (char*)As;
  char* BsB = (char*)Bs;

  for (int k0 = 0; k0 < 1024; k0 += 64) {
#pragma unroll
    for (int j = 0; j < 4; ++j) {
      u16* ldst_a = &As[(wave * 256 + j * 64) * 8];
      u16* ldst_b = &Bs[(wave * 256 + j * 64) * 8];
      gl16(Abase + aoff[j] + k0, ldst_a);
      gl16(Bbase + aoff[j] + k0, ldst_b);
    }
    __syncthreads();  // drains vmcnt -> LDS tiles ready
#pragma unroll
    for (int kk = 0; kk < 2; ++kk) {
      bf16x8 am[4], bn[4];
#pragma unroll
      for (int mi = 0; mi < 4; ++mi) {
        int row = wm * 64 + mi * 16 + lr;
        ABUn u;
        u.u = *(const ushort8*)(AsB + ((u32)(row * 128 + ((kk * 64 + lg * 16) ^ ((row & 7) << 4)))));
        am[mi] = u.b;
      }
#pragma unroll
      for (int ni = 0; ni < 4; ++ni) {
        int row = wn * 64 + ni * 16 + lr;
        ABUn u;
        u.u = *(const ushort8*)(BsB + ((u32)(row * 128 + ((kk * 64 + lg * 16) ^ ((row & 7) << 4)))));
        bn[ni] = u.b;
      }
#pragma unroll
      for (int mi = 0; mi < 4; ++mi)
#pragma unroll
        for (int ni = 0; ni < 4; ++ni)
          acc[mi][ni] = __builtin_amdgcn_mfma_f32_16x16x32_bf16(am[mi], bn[ni], acc[mi][ni], 0, 0, 0);
    }
    __syncthreads();
  }

#pragma unroll
  for (int mi = 0; mi < 4; ++mi)
#pragma unroll
    for (int ni = 0; ni < 4; ++ni) {
      int m = m0 + wm * 64 + mi * 16 + lg * 4;  // base t (r adds 0..3)
      int n = n0 + wn * 64 + ni * 16 + lr;
      if (EPI == 0) {
        int part = n >> 10, c = n & 1023;
        int h = c >> 6, d = c & 63;
        int b = m >> 11, t = m & 2047;
        if (part == 2) {
          ushort4v pv;
#pragma unroll
          for (int r = 0; r < 4; ++r) pv[r] = f2bf(acc[mi][ni][r]);
          *(ushort4v*)&Vb[((b * H_ + h) * D_ + d) * T_ + t] = pv;
        } else {
#pragma unroll
          for (int r = 0; r < 4; ++r) {
            float v = acc[mi][ni][r];
            if (part == 0)
              Qb[((b * H_ + h) * T_ + t + r) * D_ + d] = f2bf(v * 0.18033688f);  // 0.125*log2(e)
            else
              Kb[((b * H_ + h) * T_ + t + r) * D_ + d] = f2bf(v);
          }
        }
      } else {
#pragma unroll
        for (int r = 0; r < 4; ++r)
          Out[(m + r) * 1024 + n] = acc[mi][ni][r] + bias[n];
      }
    }
}

// ---------------- flash attention v5: 8-wave, causal-paired, defer-max ----
// grid (4, 64) = 256 blocks, uniform work: block bx processes q-tiles
// bx*256 and 1792-bx*256 (36 staged chunks total). 8 waves x 32 q-rows.
// KVBLK=64, swapped QK^T, double-buffered LDS K + V^T via global_load_lds.
__global__ __launch_bounds__(512, 4) void attn_kernel(
    const u16* __restrict__ Qb, const u16* __restrict__ Kb,
    const u16* __restrict__ Vt, u16* __restrict__ Ob) {
  __shared__ u16 smem[4][4096];  // [0..1]=K dbuf, [2..3]=V^T dbuf; reused as epi scratch
  const int bh = blockIdx.y;
  const int tid = threadIdx.x;
  const int lane = tid & 63, wave = tid >> 6;
  const int hi = lane >> 5, ln = lane & 31;
  const int hh = bh & (H_ - 1), bb = bh >> 4;

  const u16* Qh = Qb + bh * (T_ * D_);
  const u16* Kh = Kb + bh * (T_ * D_);
  const u16* Vh = Vt + bh * (T_ * D_);

  // staging: one 16B slot per thread per tile (512 slots = 8KB tile)
  const int srow = tid >> 3;                    // 0..63
  const int scol = (tid & 7) ^ (srow & 7);      // pre-swizzled global 16B-chunk
  u16* kdst = &smem[0][(wave * 64) * 8];        // wave-uniform dest (buf 0); +8KB for buf1 etc.

#pragma unroll
  for (int pass = 0; pass < 2; ++pass) {
    const int q0 = pass ? (1792 - (int)blockIdx.x * 256) : ((int)blockIdx.x * 256);
    const int qw0 = q0 + wave * 32;

    // Q B-fragments: lane = q-col ln; k = d = ks*16 + hi*8 + j
    bf16x8 qf[4];
    {
      const u16* qr = Qh + (qw0 + ln) * 64 + hi * 8;
#pragma unroll
      for (int ks = 0; ks < 4; ++ks)
        qf[ks] = __builtin_bit_cast(bf16x8, *(const ushort8*)(qr + ks * 16));
    }

    f32x16 o[2];
#pragma unroll
    for (int dt = 0; dt < 2; ++dt)
#pragma unroll
      for (int i = 0; i < 16; ++i) o[dt][i] = 0.0f;
    float m = -1e30f, l = 0.0f;

    const int nchunk = q0 / 64 + 4;

    __syncthreads();  // smem free (prev pass epilogue done)
    // prologue: stage chunk 0 into buf 0
    gl16(Kh + srow * 64 + scol * 8, kdst);
    gl16(Vh + srow * 2048 + scol * 8, kdst + 2 * 4096);
    __syncthreads();

    for (int ch = 0; ch < nchunk; ++ch) {
      const int kv0 = ch * 64;
      const int cur = ch & 1;
      if (ch + 1 < nchunk) {  // async prefetch next chunk into other buffer
        const int kn = kv0 + 64;
        gl16(Kh + (kn + srow) * 64 + scol * 8, kdst + (cur ^ 1) * 4096);
        gl16(Vh + srow * 2048 + kn + scol * 8, kdst + (2 + (cur ^ 1)) * 4096);
      }
      if (kv0 <= qw0 + 31) {  // wave-uniform: skip fully-masked chunks
        const char* Kc = (const char*)smem[cur];
        const char* Vc = (const char*)smem[2 + cur];
        f32x16 s0, s1;
#pragma unroll
        for (int i = 0; i < 16; ++i) { s0[i] = 0.0f; s1[i] = 0.0f; }
        __builtin_amdgcn_s_setprio(1);
#pragma unroll
        for (int ks = 0; ks < 4; ++ks) {
          int r0 = ln, r1 = 32 + ln;
          bf16x8 kf0 = __builtin_bit_cast(bf16x8,
              *(const ushort8*)(Kc + r0 * 128 + (u32)((ks * 32 + hi * 16) ^ ((r0 & 7) << 4))));
          bf16x8 kf1 = __builtin_bit_cast(bf16x8,
              *(const ushort8*)(Kc + r1 * 128 + (u32)((ks * 32 + hi * 16) ^ ((r1 & 7) << 4))));
          s0 = __builtin_amdgcn_mfma_f32_32x32x16_bf16(kf0, qf[ks], s0, 0, 0, 0);
          s1 = __builtin_amdgcn_mfma_f32_32x32x16_bf16(kf1, qf[ks], s1, 0, 0, 0);
        }
        __builtin_amdgcn_s_setprio(0);

        const int qg = qw0 + ln;
        if ((kv0 + 63) > qw0) {  // partial chunk: causal mask
#pragma unroll
          for (int r = 0; r < 16; ++r) {
            int R = (r & 3) + 8 * (r >> 2) + 4 * hi;
            s0[r] = (kv0 + R > qg) ? -1e30f : s0[r];
            s1[r] = (kv0 + 32 + R > qg) ? -1e30f : s1[r];
          }
        }
        // tree max
        float mx[8];
#pragma unroll
        for (int i = 0; i < 8; ++i)
          mx[i] = fmaxf(fmaxf(s0[i], s0[i + 8]), fmaxf(s1[i], s1[i + 8]));
#pragma unroll
        for (int i = 0; i < 4; ++i) mx[i] = fmaxf(mx[i], mx[i + 4]);
        float cm = fmaxf(fmaxf(mx[0], mx[1]), fmaxf(mx[2], mx[3]));
        cm = fmaxf(cm, __shfl_xor(cm, 32));
        // defer-max (T13, log2 domain): skip rescale while tile max grows <= 8
        // (P bounded by 2^8; first processed chunk always rescales since m=-1e30)
        if (!__all(cm <= m + 8.0f)) {
          float mn = fmaxf(m, cm);
          float fsc = fexp2(m - mn);
          m = mn;
          l *= fsc;
#pragma unroll
          for (int dt = 0; dt < 2; ++dt)
#pragma unroll
            for (int i = 0; i < 16; ++i) o[dt][i] *= fsc;
        }
#pragma unroll
        for (int r = 0; r < 16; ++r) {
          s0[r] = fexp2(s0[r] - m);
          s1[r] = fexp2(s1[r] - m);
        }
        // tree sum
        float sm[8];
#pragma unroll
        for (int i = 0; i < 8; ++i) sm[i] = (s0[i] + s0[i + 8]) + (s1[i] + s1[i + 8]);
#pragma unroll
        for (int i = 0; i < 4; ++i) sm[i] += sm[i + 4];
        float ssum = (sm[0] + sm[1]) + (sm[2] + sm[3]);
        ssum += __shfl_xor(ssum, 32);
        l += ssum;

        // pack P->bf16; v_permlane32_swap builds B-fragments in-register
        bf16x8 pb[4];
#pragma unroll
        for (int sub = 0; sub < 2; ++sub) {
          u32 a0, a1, a2, a3, a4, a5, a6, a7;
          if (sub == 0) {
            a0 = pkbf(s0[0], s0[1]);  a1 = pkbf(s0[2], s0[3]);
            a2 = pkbf(s0[4], s0[5]);  a3 = pkbf(s0[6], s0[7]);
            a4 = pkbf(s0[8], s0[9]);  a5 = pkbf(s0[10], s0[11]);
            a6 = pkbf(s0[12], s0[13]); a7 = pkbf(s0[14], s0[15]);
          } else {
            a0 = pkbf(s1[0], s1[1]);  a1 = pkbf(s1[2], s1[3]);
            a2 = pkbf(s1[4], s1[5]);  a3 = pkbf(s1[6], s1[7]);
            a4 = pkbf(s1[8], s1[9]);  a5 = pkbf(s1[10], s1[11]);
            a6 = pkbf(s1[12], s1[13]); a7 = pkbf(s1[14], s1[15]);
          }
          // swap(a_lo_pair): vdst.hi <-> src.lo
          asm volatile("v_permlane32_swap_b32 %0, %1" : "+v"(a0), "+v"(a2));
          asm volatile("v_permlane32_swap_b32 %0, %1" : "+v"(a1), "+v"(a3));
          asm volatile("v_permlane32_swap_b32 %0, %1" : "+v"(a4), "+v"(a6));
          asm volatile("v_permlane32_swap_b32 %0, %1" : "+v"(a5), "+v"(a7));
          u32x4 w0, w1;
          w0[0] = a0; w0[1] = a1; w0[2] = a2; w0[3] = a3;
          w1[0] = a4; w1[1] = a5; w1[2] = a6; w1[3] = a7;
          pb[sub * 2 + 0] = __builtin_bit_cast(bf16x8, w0);
          pb[sub * 2 + 1] = __builtin_bit_cast(bf16x8, w1);
        }
        // PV: O^T[d][q] += V^T[d][kv] * P^T[kv][q]
        __builtin_amdgcn_s_setprio(1);
#pragma unroll
        for (int dt = 0; dt < 2; ++dt) {
          int r = dt * 32 + ln;
          u32 rs = (u32)((r & 7) << 4);
#pragma unroll
          for (int ks = 0; ks < 4; ++ks) {
            bf16x8 vfk = __builtin_bit_cast(bf16x8,
                *(const ushort8*)(Vc + r * 128 + (u32)((ks * 32 + hi * 16) ^ rs)));
            o[dt] = __builtin_amdgcn_mfma_f32_32x32x16_bf16(vfk, pb[ks], o[dt], 0, 0, 0);
          }
        }
        __builtin_amdgcn_s_setprio(0);
      }
      __syncthreads();
    }

    // epilogue: normalize, transpose O^T -> O through per-wave LDS, coalesced store
    __syncthreads();
    char* Wb = ((char*)smem) + wave * 4096;  // 4KB per wave (8 waves = full 32KB)
    {
      float inv = 1.0f / l;
      int q = ln;
      u32 rs = (u32)((q & 7) << 4);
#pragma unroll
      for (int dt = 0; dt < 2; ++dt)
#pragma unroll
        for (int p = 0; p < 8; ++p) {
          u32 w = pkbf(o[dt][2 * p] * inv, o[dt][2 * p + 1] * inv);
          int d = dt * 32 + ((2 * p) & 3) + 8 * (p >> 1) + 4 * hi;
          *(u32*)(Wb + ((u32)(q * 128 + d * 2) ^ rs)) = w;
        }
    }
    asm volatile("s_waitcnt lgkmcnt(0)" ::: "memory");
#pragma unroll
    for (int j = 0; j < 4; ++j) {
      int idx = j * 64 + lane;
      int row = idx >> 3, sp = idx & 7;
      ushort8 v = *(const ushort8*)(Wb + row * 128 + (u32)((sp * 16) ^ ((row & 7) << 4)));
      *(ushort8*)(Ob + (bb * T_ + qw0 + row) * C_ + hh * 64 + sp * 8) = v;
    }
  }
}

// ---------------- launch ----------------
extern "C" void kernel_launch(void* const* d_in, const int* in_sizes, int n_in,
                              void* d_out, int out_size, void* d_ws, size_t ws_size,
                              hipStream_t stream) {
  const float* x = (const float*)d_in[0];
  const float* w_qkv = (const float*)d_in[1];
  const float* w_proj = (const float*)d_in[2];
  const float* b_proj = (const float*)d_in[3];
  float* out = (float*)d_out;

  char* ws = (char*)d_ws;
  u16* xb = (u16*)(ws);                               // 16 MB  [M][C] bf16
  u16* wqT = (u16*)(ws + 16777216);                   // 6 MB   [3C][C] bf16
  u16* wpT = (u16*)(ws + 16777216 + 6291456);         // 2 MB   [C][C] bf16
  u16* Qb = (u16*)(ws + 25165824);                    // 16 MB  [B*H][T][D]
  u16* Kb = (u16*)(ws + 25165824 + 16777216);         // 16 MB  [B*H][T][D]
  u16* Vt = (u16*)(ws + 25165824 + 2 * 16777216);     // 16 MB  [B*H][D][T] (transposed)
  u16* Ob = xb;  // reuse x's bf16 buffer

  cast_kernel<<<(M_ * C_ / 4 + 255) / 256, 256, 0, stream>>>(x, xb, M_ * C_ / 4);
  dim3 tb(32, 8);
  transpose_cast_kernel<<<dim3(3 * C_ / 32, C_ / 32), tb, 0, stream>>>(w_qkv, wqT, C_, 3 * C_);
  transpose_cast_kernel<<<dim3(C_ / 32, C_ / 32), tb, 0, stream>>>(w_proj, wpT, C_, C_);

  gemm_bt<0><<<dim3(3 * C_ / 128, M_ / 128), 256, 0, stream>>>(
      xb, wqT, Qb, Kb, Vt, nullptr, nullptr);

  attn_kernel<<<dim3(T_ / 512, B_ * H_), 512, 0, stream>>>(Qb, Kb, Vt, Ob);

  gemm_bt<1><<<dim3(C_ / 128, M_ / 128), 256, 0, stream>>>(
      Ob, wpT, nullptr, nullptr, nullptr, out, b_proj);
}